// Round 5
// baseline (962.311 us; speedup 1.0000x reference)
//
#include <hip/hip_runtime.h>
#include <hip/hip_bf16.h>

typedef float f32x4 __attribute__((ext_vector_type(4)));
typedef short s16x8 __attribute__((ext_vector_type(8)));
typedef unsigned int u32;

__device__ __forceinline__ short f2bf(float f) {
    union { float f; u32 u; } c; c.f = f;
    return (short)((c.u + 0x8000u) >> 16);
}
__device__ __forceinline__ float bf2f(u32 v) {
    union { u32 u; float f; } c; c.u = v << 16; return c.f;
}
__device__ __forceinline__ u32 pk2(float a, float b) {
    return (u32)(unsigned short)f2bf(a) | ((u32)(unsigned short)f2bf(b) << 16);
}
__device__ __forceinline__ s16x8 cvt8(float4 f0, float4 f1) {
    s16x8 v;
    v[0] = f2bf(f0.x); v[1] = f2bf(f0.y); v[2] = f2bf(f0.z); v[3] = f2bf(f0.w);
    v[4] = f2bf(f1.x); v[5] = f2bf(f1.y); v[6] = f2bf(f1.z); v[7] = f2bf(f1.w);
    return v;
}

// ---------------- weight packing: MFMA B-fragment order ----------------
__global__ void pack_w(const float* __restrict__ W, short* __restrict__ out,
                       int Kreal, int N, int nbTot, int total) {
    int tid = blockIdx.x * 256 + threadIdx.x;
    if (tid >= total) return;
    int j  = tid & 7;
    int l  = (tid >> 3) & 63;
    int blk = tid >> 9;            // ks*nbTot + nb
    int nb = blk % nbTot, ks = blk / nbTot;
    int k = ks * 32 + (l >> 4) * 8 + j;
    int n = nb * 16 + (l & 15);
    out[tid] = (k < Kreal) ? f2bf(W[(long)k * N + n]) : (short)0;
}

// ---------------- wave-local layernorm over 256 cols, 32 rows ----------------
__device__ __forceinline__ void ln_wave2(f32x4 (&acc)[2][16], const float* __restrict__ g,
                                         const float* __restrict__ bl, int r) {
#pragma unroll
    for (int mi = 0; mi < 2; ++mi)
#pragma unroll
        for (int j = 0; j < 4; ++j) {
            float s = 0.f, q = 0.f;
#pragma unroll
            for (int ni = 0; ni < 16; ++ni) { float v = acc[mi][ni][j]; s += v; q += v * v; }
#pragma unroll
            for (int m = 1; m < 16; m <<= 1) { s += __shfl_xor(s, m, 64); q += __shfl_xor(q, m, 64); }
            float mean = s * (1.f / 256.f);
            float var  = fmaxf(q * (1.f / 256.f) - mean * mean, 0.f);
            float rstd = rsqrtf(var + 1e-5f);
#pragma unroll
            for (int ni = 0; ni < 16; ++ni) acc[mi][ni][j] = (acc[mi][ni][j] - mean) * rstd;
        }
#pragma unroll
    for (int ni = 0; ni < 16; ++ni) {
        float gg = g[ni * 16 + r], bb = bl[ni * 16 + r];
#pragma unroll
        for (int mi = 0; mi < 2; ++mi)
#pragma unroll
            for (int j = 0; j < 4; ++j) acc[mi][ni][j] = acc[mi][ni][j] * gg + bb;
    }
}

#define MFMA(a, b, c) __builtin_amdgcn_mfma_f32_16x16x32_bf16((a), (b), (c), 0, 0, 0)

// ---------------- main fused kernel: 1 wave per block, 32 rows per wave ----------------
__global__ __launch_bounds__(64, 2) void deq_main(
    const float* __restrict__ x, const float* __restrict__ z,
    const float* __restrict__ b_inp, const float* __restrict__ g_lni, const float* __restrict__ b_lni,
    const float* __restrict__ b1, const float* __restrict__ g_ln1, const float* __restrict__ b_ln1,
    const float* __restrict__ b2, const float* __restrict__ g_ln2, const float* __restrict__ b_ln2,
    const float* __restrict__ g_ln3, const float* __restrict__ b_ln3,
    const float* __restrict__ b_out,
    const s16x8* __restrict__ Wp1, const s16x8* __restrict__ Wp2,
    const s16x8* __restrict__ WpI, const s16x8* __restrict__ WpO,
    float* __restrict__ out_dx, float* __restrict__ out_z)
{
    __shared__ __align__(16) short T_sh[32 * 256];   // 16 KB wave-local transpose buffer

    const int lane = threadIdx.x & 63;
    const int r = lane & 15, kg = lane >> 4;
    const long r0 = (long)blockIdx.x * 32;
    const int swz = (r & 7) << 4;                    // full 8-slot spread (2-way max on b128 reads)

    f32x4 acc[2][16];

    // ================= GEMM1: z @ W1 (+b1 as C-init) =================
#pragma unroll
    for (int ni = 0; ni < 16; ++ni) {
        float bb = b1[ni * 16 + r];
#pragma unroll
        for (int mi = 0; mi < 2; ++mi) acc[mi][ni] = (f32x4){bb, bb, bb, bb};
    }
    {
        const float* z0 = z + (r0 + r) * 256 + kg * 8;
        const float* z1r = z + (r0 + 16 + r) * 256 + kg * 8;
        s16x8 bA[8], bB[8];
#pragma unroll
        for (int ni = 0; ni < 8; ++ni) bA[ni] = Wp1[ni * 64 + lane];
#pragma unroll
        for (int ni = 0; ni < 8; ++ni) bB[ni] = Wp1[(8 + ni) * 64 + lane];
#pragma unroll
        for (int ks = 0; ks < 8; ++ks) {
            const float4* p0 = (const float4*)(z0 + ks * 32);
            const float4* p1 = (const float4*)(z1r + ks * 32);
            s16x8 a0 = cvt8(p0[0], p0[1]);
            s16x8 a1 = cvt8(p1[0], p1[1]);
#pragma unroll
            for (int ni = 0; ni < 8; ++ni) {
                acc[0][ni] = MFMA(a0, bA[ni], acc[0][ni]);
                acc[1][ni] = MFMA(a1, bA[ni], acc[1][ni]);
            }
            if (ks < 7) {
#pragma unroll
                for (int ni = 0; ni < 8; ++ni) bA[ni] = Wp1[((ks + 1) * 16 + ni) * 64 + lane];
            }
#pragma unroll
            for (int ni = 0; ni < 8; ++ni) {
                acc[0][8 + ni] = MFMA(a0, bB[ni], acc[0][8 + ni]);
                acc[1][8 + ni] = MFMA(a1, bB[ni], acc[1][8 + ni]);
            }
            if (ks < 7) {
#pragma unroll
                for (int ni = 0; ni < 8; ++ni) bB[ni] = Wp1[((ks + 1) * 16 + 8 + ni) * 64 + lane];
            }
        }
    }

    // issue x loads early (HBM latency hides under LN1 + z1 LDS writes)
    float4 xr[2][4];
    {
        const float* x0 = x + (r0 + r) * 48;
        const float* x1 = x + (r0 + 16 + r) * 48;
        xr[0][0] = ((const float4*)(x0 + kg * 8))[0];
        xr[0][1] = ((const float4*)(x0 + kg * 8))[1];
        xr[1][0] = ((const float4*)(x1 + kg * 8))[0];
        xr[1][1] = ((const float4*)(x1 + kg * 8))[1];
        if (kg < 2) {
            xr[0][2] = ((const float4*)(x0 + 32 + kg * 8))[0];
            xr[0][3] = ((const float4*)(x0 + 32 + kg * 8))[1];
            xr[1][2] = ((const float4*)(x1 + 32 + kg * 8))[0];
            xr[1][3] = ((const float4*)(x1 + 32 + kg * 8))[1];
        } else {
            xr[0][2] = xr[0][3] = xr[1][2] = xr[1][3] = (float4){0.f, 0.f, 0.f, 0.f};
        }
    }

    // relu + LN1 -> z1
#pragma unroll
    for (int mi = 0; mi < 2; ++mi)
#pragma unroll
        for (int ni = 0; ni < 16; ++ni)
#pragma unroll
            for (int j = 0; j < 4; ++j) acc[mi][ni][j] = fmaxf(acc[mi][ni][j], 0.f);
    ln_wave2(acc, g_ln1, b_ln1, r);

    // pack z1 into registers (residual copy) and write bf16 z1 to LDS for GEMM2 A-frags
    u32 z1p[2][16][2];
#pragma unroll
    for (int mi = 0; mi < 2; ++mi)
#pragma unroll
        for (int ni = 0; ni < 16; ++ni) {
            z1p[mi][ni][0] = pk2(acc[mi][ni][0], acc[mi][ni][1]);
            z1p[mi][ni][1] = pk2(acc[mi][ni][2], acc[mi][ni][3]);
        }
#pragma unroll
    for (int mi = 0; mi < 2; ++mi)
#pragma unroll
        for (int j = 0; j < 4; ++j) {
            int row = mi * 16 + kg * 4 + j;
            int rb = row * 512, sw = (row & 7) << 4;
#pragma unroll
            for (int ni = 0; ni < 16; ++ni)
                *(short*)((char*)T_sh + ((rb + (ni * 16 + r) * 2) ^ sw)) =
                    (short)(z1p[mi][ni][j >> 1] >> ((j & 1) * 16));
        }

    // ================= x-GEMM: x @ W_inp (+b_inp as C-init) =================
#pragma unroll
    for (int ni = 0; ni < 16; ++ni) {
        float bb = b_inp[ni * 16 + r];
#pragma unroll
        for (int mi = 0; mi < 2; ++mi) acc[mi][ni] = (f32x4){bb, bb, bb, bb};
    }
    {
        s16x8 a00 = cvt8(xr[0][0], xr[0][1]);
        s16x8 a10 = cvt8(xr[1][0], xr[1][1]);
        s16x8 a01 = cvt8(xr[0][2], xr[0][3]);
        s16x8 a11 = cvt8(xr[1][2], xr[1][3]);
#pragma unroll
        for (int ni = 0; ni < 16; ++ni) {
            s16x8 b = WpI[ni * 64 + lane];
            acc[0][ni] = MFMA(a00, b, acc[0][ni]);
            acc[1][ni] = MFMA(a10, b, acc[1][ni]);
        }
#pragma unroll
        for (int ni = 0; ni < 16; ++ni) {
            s16x8 b = WpI[(16 + ni) * 64 + lane];
            acc[0][ni] = MFMA(a01, b, acc[0][ni]);
            acc[1][ni] = MFMA(a11, b, acc[1][ni]);
        }
    }
    ln_wave2(acc, g_lni, b_lni, r);       // acc = xinp

    // + b2 (C-init for GEMM2)
#pragma unroll
    for (int ni = 0; ni < 16; ++ni) {
        float bb = b2[ni * 16 + r];
#pragma unroll
        for (int mi = 0; mi < 2; ++mi)
#pragma unroll
            for (int j = 0; j < 4; ++j) acc[mi][ni][j] += bb;
    }

    // ================= GEMM2: + z1 @ W2 (A from LDS) =================
    {
        s16x8 bA[8], bB[8];
#pragma unroll
        for (int ni = 0; ni < 8; ++ni) bA[ni] = Wp2[ni * 64 + lane];
#pragma unroll
        for (int ni = 0; ni < 8; ++ni) bB[ni] = Wp2[(8 + ni) * 64 + lane];
#pragma unroll
        for (int ks = 0; ks < 8; ++ks) {
            int off = (ks * 64 + kg * 16) ^ swz;
            s16x8 a0 = *(const s16x8*)((const char*)T_sh + r * 512 + off);
            s16x8 a1 = *(const s16x8*)((const char*)T_sh + r * 512 + 8192 + off);
#pragma unroll
            for (int ni = 0; ni < 8; ++ni) {
                acc[0][ni] = MFMA(a0, bA[ni], acc[0][ni]);
                acc[1][ni] = MFMA(a1, bA[ni], acc[1][ni]);
            }
            if (ks < 7) {
#pragma unroll
                for (int ni = 0; ni < 8; ++ni) bA[ni] = Wp2[((ks + 1) * 16 + ni) * 64 + lane];
            }
#pragma unroll
            for (int ni = 0; ni < 8; ++ni) {
                acc[0][8 + ni] = MFMA(a0, bB[ni], acc[0][8 + ni]);
                acc[1][8 + ni] = MFMA(a1, bB[ni], acc[1][8 + ni]);
            }
            if (ks < 7) {
#pragma unroll
                for (int ni = 0; ni < 8; ++ni) bB[ni] = Wp2[((ks + 1) * 16 + 8 + ni) * 64 + lane];
            }
        }
    }
    ln_wave2(acc, g_ln2, b_ln2, r);       // acc = inner

    // ---- z_out = LN3(relu(z1 + inner)) ; z1 from registers ----
#pragma unroll
    for (int mi = 0; mi < 2; ++mi)
#pragma unroll
        for (int ni = 0; ni < 16; ++ni) {
            acc[mi][ni][0] = fmaxf(acc[mi][ni][0] + bf2f(z1p[mi][ni][0] & 0xffffu), 0.f);
            acc[mi][ni][1] = fmaxf(acc[mi][ni][1] + bf2f(z1p[mi][ni][0] >> 16), 0.f);
            acc[mi][ni][2] = fmaxf(acc[mi][ni][2] + bf2f(z1p[mi][ni][1] & 0xffffu), 0.f);
            acc[mi][ni][3] = fmaxf(acc[mi][ni][3] + bf2f(z1p[mi][ni][1] >> 16), 0.f);
        }
    ln_wave2(acc, g_ln3, b_ln3, r);       // acc = z_out

    // write z_out (bf16) to LDS (source for out-GEMM A and the coalesced f32 copy)
#pragma unroll
    for (int mi = 0; mi < 2; ++mi)
#pragma unroll
        for (int j = 0; j < 4; ++j) {
            int row = mi * 16 + kg * 4 + j;
            int rb = row * 512, sw = (row & 7) << 4;
#pragma unroll
            for (int ni = 0; ni < 16; ++ni)
                *(short*)((char*)T_sh + ((rb + (ni * 16 + r) * 2) ^ sw)) = f2bf(acc[mi][ni][j]);
        }

    // ================= out-GEMM: dx = z_out @ W_out (+b_out as C-init) =================
    f32x4 ao[2][2];
#pragma unroll
    for (int ni = 0; ni < 2; ++ni) {
        float bb = b_out[ni * 16 + r];
#pragma unroll
        for (int mi = 0; mi < 2; ++mi) ao[mi][ni] = (f32x4){bb, bb, bb, bb};
    }
#pragma unroll
    for (int ks = 0; ks < 8; ++ks) {
        int off = (ks * 64 + kg * 16) ^ swz;
        s16x8 a0 = *(const s16x8*)((const char*)T_sh + r * 512 + off);
        s16x8 a1 = *(const s16x8*)((const char*)T_sh + r * 512 + 8192 + off);
#pragma unroll
        for (int ni = 0; ni < 2; ++ni) {
            s16x8 b = WpO[(ks * 2 + ni) * 64 + lane];
            ao[0][ni] = MFMA(a0, b, ao[0][ni]);
            ao[1][ni] = MFMA(a1, b, ao[1][ni]);
        }
    }
#pragma unroll
    for (int mi = 0; mi < 2; ++mi)
#pragma unroll
        for (int ni = 0; ni < 2; ++ni)
#pragma unroll
            for (int j = 0; j < 4; ++j)
                out_dx[(r0 + mi * 16 + kg * 4 + j) * 32 + ni * 16 + r] = ao[mi][ni][j];

    // ---- coalesced out_z copy: LDS bf16 -> global f32, 1KB/instr ----
    {
        float* zo = out_z + r0 * 256;
#pragma unroll
        for (int it = 0; it < 16; ++it) {
            int row = it * 2 + (lane >> 5);
            int cb = (lane & 31) * 16;                  // byte offset within row (8 bf16)
            int addr = (row * 512 + cb) ^ ((row & 7) << 4);
            int4 w = *(const int4*)((const char*)T_sh + addr);
            float4 o0, o1;
            o0.x = bf2f((unsigned)w.x & 0xffffu); o0.y = bf2f((unsigned)w.x >> 16);
            o0.z = bf2f((unsigned)w.y & 0xffffu); o0.w = bf2f((unsigned)w.y >> 16);
            o1.x = bf2f((unsigned)w.z & 0xffffu); o1.y = bf2f((unsigned)w.z >> 16);
            o1.z = bf2f((unsigned)w.w & 0xffffu); o1.w = bf2f((unsigned)w.w >> 16);
            int e = row * 256 + (lane & 31) * 8;
            *(float4*)(zo + e) = o0;
            *(float4*)(zo + e + 4) = o1;
        }
    }
}

extern "C" void kernel_launch(void* const* d_in, const int* in_sizes, int n_in,
                              void* d_out, int out_size, void* d_ws, size_t ws_size,
                              hipStream_t stream) {
    const float* x      = (const float*)d_in[0];
    const float* z      = (const float*)d_in[1];
    const float* W_inp  = (const float*)d_in[2];
    const float* b_inp  = (const float*)d_in[3];
    const float* g_lni  = (const float*)d_in[4];
    const float* b_lni  = (const float*)d_in[5];
    const float* W1     = (const float*)d_in[6];
    const float* b1     = (const float*)d_in[7];
    const float* g_ln1  = (const float*)d_in[8];
    const float* b_ln1  = (const float*)d_in[9];
    const float* W2     = (const float*)d_in[10];
    const float* b2     = (const float*)d_in[11];
    const float* g_ln2  = (const float*)d_in[12];
    const float* b_ln2  = (const float*)d_in[13];
    const float* g_ln3  = (const float*)d_in[14];
    const float* b_ln3  = (const float*)d_in[15];
    const float* W_out  = (const float*)d_in[16];
    const float* b_out  = (const float*)d_in[17];

    short* Wp1 = (short*)d_ws;            // 8*16*64*8  = 65536 bf16
    short* Wp2 = Wp1 + 65536;             // 65536
    short* WpI = Wp2 + 65536;             // 2*16*64*8  = 16384
    short* WpO = WpI + 16384;             // 8*2*64*8   = 8192

    pack_w<<<256, 256, 0, stream>>>(W1,    Wp1, 256, 256, 16, 65536);
    pack_w<<<256, 256, 0, stream>>>(W2,    Wp2, 256, 256, 16, 65536);
    pack_w<<< 64, 256, 0, stream>>>(W_inp, WpI,  48, 256, 16, 16384);
    pack_w<<< 32, 256, 0, stream>>>(W_out, WpO, 256,  32,  2,  8192);

    const long B = 262144;
    float* out_dx = (float*)d_out;
    float* out_z  = out_dx + B * 32;
    deq_main<<<B / 32, 64, 0, stream>>>(x, z, b_inp, g_lni, b_lni,
                                        b1, g_ln1, b_ln1, b2, g_ln2, b_ln2,
                                        g_ln3, b_ln3, b_out,
                                        (const s16x8*)Wp1, (const s16x8*)Wp2,
                                        (const s16x8*)WpI, (const s16x8*)WpO,
                                        out_dx, out_z);
}

// Round 6
// 465.750 us; speedup vs baseline: 2.0662x; 2.0662x over previous
//
#include <hip/hip_runtime.h>
#include <hip/hip_bf16.h>

typedef float f32x4 __attribute__((ext_vector_type(4)));
typedef short s16x8 __attribute__((ext_vector_type(8)));
typedef unsigned int u32;

__device__ __forceinline__ short f2bf(float f) {
    union { float f; u32 u; } c; c.f = f;
    return (short)((c.u + 0x8000u) >> 16);
}
__device__ __forceinline__ float bf2f(u32 v) {
    union { u32 u; float f; } c; c.u = v << 16; return c.f;
}
__device__ __forceinline__ s16x8 cvt8(float4 f0, float4 f1) {
    s16x8 v;
    v[0] = f2bf(f0.x); v[1] = f2bf(f0.y); v[2] = f2bf(f0.z); v[3] = f2bf(f0.w);
    v[4] = f2bf(f1.x); v[5] = f2bf(f1.y); v[6] = f2bf(f1.z); v[7] = f2bf(f1.w);
    return v;
}

// ---------------- weight packing: MFMA B-fragment order ----------------
__global__ void pack_w(const float* __restrict__ W, short* __restrict__ out,
                       int Kreal, int N, int nbTot, int total) {
    int tid = blockIdx.x * 256 + threadIdx.x;
    if (tid >= total) return;
    int j  = tid & 7;
    int l  = (tid >> 3) & 63;
    int blk = tid >> 9;            // ks*nbTot + nb
    int nb = blk % nbTot, ks = blk / nbTot;
    int k = ks * 32 + (l >> 4) * 8 + j;
    int n = nb * 16 + (l & 15);
    out[tid] = (k < Kreal) ? f2bf(W[(long)k * N + n]) : (short)0;
}

#define MFMA(a, b, c) __builtin_amdgcn_mfma_f32_16x16x32_bf16((a), (b), (c), 0, 0, 0)
#define TS 264   // T_sh row stride in shorts: 528 B = 33*16 B (16B-aligned, bank-rotating)

// ---------------- cross-wave layernorm over 256 feats (each wave owns 128) ----------------
// acc[mi][ni][j]: batch row = mi*16 + kg*4 + j, feat = fb + ni*16 + r.
__device__ __forceinline__ void ln_cw(f32x4 (&acc)[2][8], const float* __restrict__ g,
                                      const float* __restrict__ bl,
                                      float2 (*red)[2], int r, int kg, int w, int fb) {
#pragma unroll
    for (int mi = 0; mi < 2; ++mi)
#pragma unroll
        for (int j = 0; j < 4; ++j) {
            float s = 0.f, q = 0.f;
#pragma unroll
            for (int ni = 0; ni < 8; ++ni) { float v = acc[mi][ni][j]; s += v; q += v * v; }
#pragma unroll
            for (int m = 1; m < 16; m <<= 1) { s += __shfl_xor(s, m, 64); q += __shfl_xor(q, m, 64); }
            if (r == 0) red[mi * 16 + kg * 4 + j][w] = make_float2(s, q);
        }
    __syncthreads();
#pragma unroll
    for (int mi = 0; mi < 2; ++mi)
#pragma unroll
        for (int j = 0; j < 4; ++j) {
            int row = mi * 16 + kg * 4 + j;
            float2 p0 = red[row][0], p1 = red[row][1];
            float s = p0.x + p1.x, q = p0.y + p1.y;
            float mean = s * (1.f / 256.f);
            float var  = fmaxf(q * (1.f / 256.f) - mean * mean, 0.f);
            float rstd = rsqrtf(var + 1e-5f);
#pragma unroll
            for (int ni = 0; ni < 8; ++ni)
                acc[mi][ni][j] = (acc[mi][ni][j] - mean) * rstd;
        }
#pragma unroll
    for (int ni = 0; ni < 8; ++ni) {
        float gg = g[fb + ni * 16 + r], bb = bl[fb + ni * 16 + r];
#pragma unroll
        for (int mi = 0; mi < 2; ++mi)
#pragma unroll
            for (int j = 0; j < 4; ++j) acc[mi][ni][j] = acc[mi][ni][j] * gg + bb;
    }
}

// ---------------- main fused kernel: 2 waves per block, 32 rows, feat-split ----------------
__global__ __launch_bounds__(128, 3) void deq_main(
    const float* __restrict__ x, const float* __restrict__ z,
    const float* __restrict__ b_inp, const float* __restrict__ g_lni, const float* __restrict__ b_lni,
    const float* __restrict__ b1, const float* __restrict__ g_ln1, const float* __restrict__ b_ln1,
    const float* __restrict__ b2, const float* __restrict__ g_ln2, const float* __restrict__ b_ln2,
    const float* __restrict__ g_ln3, const float* __restrict__ b_ln3,
    const float* __restrict__ b_out,
    const s16x8* __restrict__ Wp1, const s16x8* __restrict__ Wp2,
    const s16x8* __restrict__ WpI, const s16x8* __restrict__ WpO,
    float* __restrict__ out_dx, float* __restrict__ out_z)
{
    __shared__ __align__(16) short T_sh[32 * TS];     // 16.5 KB shared transpose buffer
    __shared__ float2 red_sh[4][32][2];               // 2 KB: 4 LN stat buffers

    const int tid  = threadIdx.x;
    const int w    = tid >> 6;                        // wave id: owns feats [w*128, w*128+128)
    const int lane = tid & 63;
    const int r = lane & 15, kg = lane >> 4;
    const int fb  = w * 128;                          // feature base
    const int fbn = w * 8;                            // frag-block base (16-col blocks)
    const long r0 = (long)blockIdx.x * 32;

    f32x4 acc[2][8];

    // ================= GEMM1: z @ W1 (+b1 as C-init), wave's 128-feat slice =================
#pragma unroll
    for (int ni = 0; ni < 8; ++ni) {
        float bb = b1[fb + ni * 16 + r];
        acc[0][ni] = (f32x4){bb, bb, bb, bb};
        acc[1][ni] = acc[0][ni];
    }
    {
        const float* z0  = z + (r0 + r) * 256 + kg * 8;
        const float* z1r = z + (r0 + 16 + r) * 256 + kg * 8;
        float4 p00 = ((const float4*)z0)[0],  p01 = ((const float4*)z0)[1];
        float4 p10 = ((const float4*)z1r)[0], p11 = ((const float4*)z1r)[1];
        s16x8 bA[4], bB[4];
#pragma unroll
        for (int ni = 0; ni < 4; ++ni) bA[ni] = Wp1[(fbn + ni) * 64 + lane];
#pragma unroll
        for (int ni = 0; ni < 4; ++ni) bB[ni] = Wp1[(fbn + 4 + ni) * 64 + lane];
#pragma unroll
        for (int ks = 0; ks < 8; ++ks) {
            s16x8 a0 = cvt8(p00, p01);
            s16x8 a1 = cvt8(p10, p11);
            if (ks < 7) {
                p00 = ((const float4*)(z0 + (ks + 1) * 32))[0];
                p01 = ((const float4*)(z0 + (ks + 1) * 32))[1];
                p10 = ((const float4*)(z1r + (ks + 1) * 32))[0];
                p11 = ((const float4*)(z1r + (ks + 1) * 32))[1];
            }
#pragma unroll
            for (int ni = 0; ni < 4; ++ni) {
                acc[0][ni] = MFMA(a0, bA[ni], acc[0][ni]);
                acc[1][ni] = MFMA(a1, bA[ni], acc[1][ni]);
            }
            if (ks < 7) {
#pragma unroll
                for (int ni = 0; ni < 4; ++ni) bA[ni] = Wp1[((ks + 1) * 16 + fbn + ni) * 64 + lane];
            }
#pragma unroll
            for (int ni = 0; ni < 4; ++ni) {
                acc[0][4 + ni] = MFMA(a0, bB[ni], acc[0][4 + ni]);
                acc[1][4 + ni] = MFMA(a1, bB[ni], acc[1][4 + ni]);
            }
            if (ks < 7) {
#pragma unroll
                for (int ni = 0; ni < 4; ++ni) bB[ni] = Wp1[((ks + 1) * 16 + fbn + 4 + ni) * 64 + lane];
            }
        }
    }

    // issue x loads early (latency hides under LN1 + z1 staging)
    float4 xr0a, xr0b, xr1a, xr1b, xr2a, xr2b, xr3a, xr3b;
    {
        const float* x0 = x + (r0 + r) * 48;
        const float* x1 = x + (r0 + 16 + r) * 48;
        xr0a = ((const float4*)(x0 + kg * 8))[0];
        xr0b = ((const float4*)(x0 + kg * 8))[1];
        xr1a = ((const float4*)(x1 + kg * 8))[0];
        xr1b = ((const float4*)(x1 + kg * 8))[1];
        if (kg < 2) {
            xr2a = ((const float4*)(x0 + 32 + kg * 8))[0];
            xr2b = ((const float4*)(x0 + 32 + kg * 8))[1];
            xr3a = ((const float4*)(x1 + 32 + kg * 8))[0];
            xr3b = ((const float4*)(x1 + 32 + kg * 8))[1];
        } else {
            xr2a = xr2b = xr3a = xr3b = (float4){0.f, 0.f, 0.f, 0.f};
        }
    }

    // relu + LN1 -> z1
#pragma unroll
    for (int mi = 0; mi < 2; ++mi)
#pragma unroll
        for (int ni = 0; ni < 8; ++ni)
#pragma unroll
            for (int j = 0; j < 4; ++j) acc[mi][ni][j] = fmaxf(acc[mi][ni][j], 0.f);
    ln_cw(acc, g_ln1, b_ln1, red_sh[0], r, kg, w, fb);

    // stage z1 (bf16) into shared T_sh: this wave's 128-feat slice, all 32 rows
#pragma unroll
    for (int mi = 0; mi < 2; ++mi)
#pragma unroll
        for (int j = 0; j < 4; ++j) {
            int row = mi * 16 + kg * 4 + j;
#pragma unroll
            for (int ni = 0; ni < 8; ++ni)
                T_sh[row * TS + fb + ni * 16 + r] = f2bf(acc[mi][ni][j]);
        }

    // ================= x-GEMM: x @ W_inp (+b_inp as C-init) =================
#pragma unroll
    for (int ni = 0; ni < 8; ++ni) {
        float bb = b_inp[fb + ni * 16 + r];
        acc[0][ni] = (f32x4){bb, bb, bb, bb};
        acc[1][ni] = acc[0][ni];
    }
    {
        s16x8 a00 = cvt8(xr0a, xr0b);
        s16x8 a10 = cvt8(xr1a, xr1b);
        s16x8 a01 = cvt8(xr2a, xr2b);
        s16x8 a11 = cvt8(xr3a, xr3b);
#pragma unroll
        for (int ni = 0; ni < 8; ++ni) {
            s16x8 b = WpI[(fbn + ni) * 64 + lane];
            acc[0][ni] = MFMA(a00, b, acc[0][ni]);
            acc[1][ni] = MFMA(a10, b, acc[1][ni]);
        }
#pragma unroll
        for (int ni = 0; ni < 8; ++ni) {
            s16x8 b = WpI[(16 + fbn + ni) * 64 + lane];
            acc[0][ni] = MFMA(a01, b, acc[0][ni]);
            acc[1][ni] = MFMA(a11, b, acc[1][ni]);
        }
    }
    // LN_inp (its barrier also orders z1 staging before GEMM2's reads)
    ln_cw(acc, g_lni, b_lni, red_sh[1], r, kg, w, fb);   // acc = xinp

    // + b2 (C-init for GEMM2)
#pragma unroll
    for (int ni = 0; ni < 8; ++ni) {
        float bb = b2[fb + ni * 16 + r];
#pragma unroll
        for (int mi = 0; mi < 2; ++mi)
#pragma unroll
            for (int j = 0; j < 4; ++j) acc[mi][ni][j] += bb;
    }

    // ================= GEMM2: + z1 @ W2 (A-frags from shared T_sh, full K=256) =================
    {
        const char* Tb = (const char*)T_sh;
        s16x8 bA[4], bB[4];
#pragma unroll
        for (int ni = 0; ni < 4; ++ni) bA[ni] = Wp2[(fbn + ni) * 64 + lane];
#pragma unroll
        for (int ni = 0; ni < 4; ++ni) bB[ni] = Wp2[(fbn + 4 + ni) * 64 + lane];
#pragma unroll
        for (int ks = 0; ks < 8; ++ks) {
            int off = r * (TS * 2) + ks * 64 + kg * 16;
            s16x8 a0 = *(const s16x8*)(Tb + off);
            s16x8 a1 = *(const s16x8*)(Tb + off + 16 * TS * 2);
#pragma unroll
            for (int ni = 0; ni < 4; ++ni) {
                acc[0][ni] = MFMA(a0, bA[ni], acc[0][ni]);
                acc[1][ni] = MFMA(a1, bA[ni], acc[1][ni]);
            }
            if (ks < 7) {
#pragma unroll
                for (int ni = 0; ni < 4; ++ni) bA[ni] = Wp2[((ks + 1) * 16 + fbn + ni) * 64 + lane];
            }
#pragma unroll
            for (int ni = 0; ni < 4; ++ni) {
                acc[0][4 + ni] = MFMA(a0, bB[ni], acc[0][4 + ni]);
                acc[1][4 + ni] = MFMA(a1, bB[ni], acc[1][4 + ni]);
            }
            if (ks < 7) {
#pragma unroll
                for (int ni = 0; ni < 4; ++ni) bB[ni] = Wp2[((ks + 1) * 16 + fbn + 4 + ni) * 64 + lane];
            }
        }
    }
    ln_cw(acc, g_ln2, b_ln2, red_sh[2], r, kg, w, fb);   // acc = inner

    // ---- z_out = LN3(relu(z1 + inner)); z1 re-read from T_sh (own wave's slice, still intact) ----
#pragma unroll
    for (int mi = 0; mi < 2; ++mi)
#pragma unroll
        for (int j = 0; j < 4; ++j) {
            int row = mi * 16 + kg * 4 + j;
#pragma unroll
            for (int ni = 0; ni < 8; ++ni) {
                u32 v = *(const unsigned short*)&T_sh[row * TS + fb + ni * 16 + r];
                acc[mi][ni][j] = fmaxf(acc[mi][ni][j] + bf2f(v), 0.f);
            }
        }
    ln_cw(acc, g_ln3, b_ln3, red_sh[3], r, kg, w, fb);   // acc = z_out

    // stage z_out (bf16) into T_sh (overwrites z1; safe: both waves passed LN2/LN3 barriers)
#pragma unroll
    for (int mi = 0; mi < 2; ++mi)
#pragma unroll
        for (int j = 0; j < 4; ++j) {
            int row = mi * 16 + kg * 4 + j;
#pragma unroll
            for (int ni = 0; ni < 8; ++ni)
                T_sh[row * TS + fb + ni * 16 + r] = f2bf(acc[mi][ni][j]);
        }
    __syncthreads();

    // ================= out-GEMM: dx = z_out @ W_out (+b_out); wave w does cols [w*16, w*16+16) ====
    f32x4 ao[2];
    {
        float bb = b_out[w * 16 + r];
        ao[0] = (f32x4){bb, bb, bb, bb};
        ao[1] = ao[0];
    }
    {
        const char* Tb = (const char*)T_sh;
#pragma unroll
        for (int ks = 0; ks < 8; ++ks) {
            int off = r * (TS * 2) + ks * 64 + kg * 16;
            s16x8 a0 = *(const s16x8*)(Tb + off);
            s16x8 a1 = *(const s16x8*)(Tb + off + 16 * TS * 2);
            s16x8 b = WpO[(ks * 2 + w) * 64 + lane];
            ao[0] = MFMA(a0, b, ao[0]);
            ao[1] = MFMA(a1, b, ao[1]);
        }
    }
#pragma unroll
    for (int mi = 0; mi < 2; ++mi)
#pragma unroll
        for (int j = 0; j < 4; ++j)
            out_dx[(r0 + mi * 16 + kg * 4 + j) * 32 + w * 16 + r] = ao[mi][j];

    // ---- coalesced out_z copy: T_sh bf16 -> global f32; wave w copies rows [w*16, w*16+16) ----
    {
        float* zo = out_z + r0 * 256;
        const char* Tb = (const char*)T_sh;
#pragma unroll
        for (int it = 0; it < 8; ++it) {
            int row = w * 16 + it * 2 + (lane >> 5);
            int cs = (lane & 31) * 8;                       // col in shorts
            int4 wd = *(const int4*)(Tb + row * (TS * 2) + cs * 2);
            float4 o0, o1;
            o0.x = bf2f((u32)wd.x & 0xffffu); o0.y = bf2f((u32)wd.x >> 16);
            o0.z = bf2f((u32)wd.y & 0xffffu); o0.w = bf2f((u32)wd.y >> 16);
            o1.x = bf2f((u32)wd.z & 0xffffu); o1.y = bf2f((u32)wd.z >> 16);
            o1.z = bf2f((u32)wd.w & 0xffffu); o1.w = bf2f((u32)wd.w >> 16);
            *(float4*)(zo + row * 256 + cs) = o0;
            *(float4*)(zo + row * 256 + cs + 4) = o1;
        }
    }
}

extern "C" void kernel_launch(void* const* d_in, const int* in_sizes, int n_in,
                              void* d_out, int out_size, void* d_ws, size_t ws_size,
                              hipStream_t stream) {
    const float* x      = (const float*)d_in[0];
    const float* z      = (const float*)d_in[1];
    const float* W_inp  = (const float*)d_in[2];
    const float* b_inp  = (const float*)d_in[3];
    const float* g_lni  = (const float*)d_in[4];
    const float* b_lni  = (const float*)d_in[5];
    const float* W1     = (const float*)d_in[6];
    const float* b1     = (const float*)d_in[7];
    const float* g_ln1  = (const float*)d_in[8];
    const float* b_ln1  = (const float*)d_in[9];
    const float* W2     = (const float*)d_in[10];
    const float* b2     = (const float*)d_in[11];
    const float* g_ln2  = (const float*)d_in[12];
    const float* b_ln2  = (const float*)d_in[13];
    const float* g_ln3  = (const float*)d_in[14];
    const float* b_ln3  = (const float*)d_in[15];
    const float* W_out  = (const float*)d_in[16];
    const float* b_out  = (const float*)d_in[17];

    short* Wp1 = (short*)d_ws;            // 8*16*64*8  = 65536 bf16
    short* Wp2 = Wp1 + 65536;             // 65536
    short* WpI = Wp2 + 65536;             // 2*16*64*8  = 16384
    short* WpO = WpI + 16384;             // 8*2*64*8   = 8192

    pack_w<<<256, 256, 0, stream>>>(W1,    Wp1, 256, 256, 16, 65536);
    pack_w<<<256, 256, 0, stream>>>(W2,    Wp2, 256, 256, 16, 65536);
    pack_w<<< 64, 256, 0, stream>>>(W_inp, WpI,  48, 256, 16, 16384);
    pack_w<<< 32, 256, 0, stream>>>(W_out, WpO, 256,  32,  2,  8192);

    const long B = 262144;
    float* out_dx = (float*)d_out;
    float* out_z  = out_dx + B * 32;
    deq_main<<<B / 32, 128, 0, stream>>>(x, z, b_inp, g_lni, b_lni,
                                         b1, g_ln1, b_ln1, b2, g_ln2, b_ln2,
                                         g_ln3, b_ln3, b_out,
                                         (const s16x8*)Wp1, (const s16x8*)Wp2,
                                         (const s16x8*)WpI, (const s16x8*)WpO,
                                         out_dx, out_z);
}

// Round 7
// 407.734 us; speedup vs baseline: 2.3601x; 1.1423x over previous
//
#include <hip/hip_runtime.h>
#include <hip/hip_bf16.h>

typedef float f32x4 __attribute__((ext_vector_type(4)));
typedef short s16x8 __attribute__((ext_vector_type(8)));
typedef unsigned int u32;

__device__ __forceinline__ short f2bf(float f) {
    union { float f; u32 u; } c; c.f = f;
    return (short)((c.u + 0x8000u) >> 16);
}
__device__ __forceinline__ float bf2f(u32 v) {
    union { u32 u; float f; } c; c.u = v << 16; return c.f;
}
__device__ __forceinline__ s16x8 cvt8(float4 f0, float4 f1) {
    s16x8 v;
    v[0] = f2bf(f0.x); v[1] = f2bf(f0.y); v[2] = f2bf(f0.z); v[3] = f2bf(f0.w);
    v[4] = f2bf(f1.x); v[5] = f2bf(f1.y); v[6] = f2bf(f1.z); v[7] = f2bf(f1.w);
    return v;
}

// ---------------- weight packing: MFMA B-fragment order ----------------
__global__ void pack_w(const float* __restrict__ W, short* __restrict__ out,
                       int Kreal, int N, int nbTot, int total) {
    int tid = blockIdx.x * 256 + threadIdx.x;
    if (tid >= total) return;
    int j  = tid & 7;
    int l  = (tid >> 3) & 63;
    int blk = tid >> 9;            // ks*nbTot + nb
    int nb = blk % nbTot, ks = blk / nbTot;
    int k = ks * 32 + (l >> 4) * 8 + j;
    int n = nb * 16 + (l & 15);
    out[tid] = (k < Kreal) ? f2bf(W[(long)k * N + n]) : (short)0;
}

#define MFMA(a, b, c) __builtin_amdgcn_mfma_f32_16x16x32_bf16((a), (b), (c), 0, 0, 0)
#define TS 264   // T_sh row stride in shorts: 528 B = 33*16 B (16B-aligned, bank-rotating)

// ---------------- cross-wave layernorm over 256 feats (each wave owns 128) ----------------
// acc[mi][ni][j]: batch row = mi*16 + kg*4 + j, feat = fb + ni*16 + r.
__device__ __forceinline__ void ln_cw(f32x4 (&acc)[2][8], const float* __restrict__ g,
                                      const float* __restrict__ bl,
                                      float2 (*red)[2], int r, int kg, int w, int fb) {
#pragma unroll
    for (int mi = 0; mi < 2; ++mi)
#pragma unroll
        for (int j = 0; j < 4; ++j) {
            float s = 0.f, q = 0.f;
#pragma unroll
            for (int ni = 0; ni < 8; ++ni) { float v = acc[mi][ni][j]; s += v; q += v * v; }
#pragma unroll
            for (int m = 1; m < 16; m <<= 1) { s += __shfl_xor(s, m, 64); q += __shfl_xor(q, m, 64); }
            if (r == 0) red[mi * 16 + kg * 4 + j][w] = make_float2(s, q);
        }
    __syncthreads();
#pragma unroll
    for (int mi = 0; mi < 2; ++mi)
#pragma unroll
        for (int j = 0; j < 4; ++j) {
            int row = mi * 16 + kg * 4 + j;
            float2 p0 = red[row][0], p1 = red[row][1];
            float s = p0.x + p1.x, q = p0.y + p1.y;
            float mean = s * (1.f / 256.f);
            float var  = fmaxf(q * (1.f / 256.f) - mean * mean, 0.f);
            float rstd = rsqrtf(var + 1e-5f);
#pragma unroll
            for (int ni = 0; ni < 8; ++ni)
                acc[mi][ni][j] = (acc[mi][ni][j] - mean) * rstd;
        }
#pragma unroll
    for (int ni = 0; ni < 8; ++ni) {
        float gg = g[fb + ni * 16 + r], bb = bl[fb + ni * 16 + r];
#pragma unroll
        for (int mi = 0; mi < 2; ++mi)
#pragma unroll
            for (int j = 0; j < 4; ++j) acc[mi][ni][j] = acc[mi][ni][j] * gg + bb;
    }
}

// ---------------- main fused kernel: 2 waves per block, 32 rows, feat-split ----------------
__global__ __launch_bounds__(128, 2) void deq_main(
    const float* __restrict__ x, const float* __restrict__ z,
    const float* __restrict__ b_inp, const float* __restrict__ g_lni, const float* __restrict__ b_lni,
    const float* __restrict__ b1, const float* __restrict__ g_ln1, const float* __restrict__ b_ln1,
    const float* __restrict__ b2, const float* __restrict__ g_ln2, const float* __restrict__ b_ln2,
    const float* __restrict__ g_ln3, const float* __restrict__ b_ln3,
    const float* __restrict__ b_out,
    const s16x8* __restrict__ Wp1, const s16x8* __restrict__ Wp2,
    const s16x8* __restrict__ WpI, const s16x8* __restrict__ WpO,
    float* __restrict__ out_dx, float* __restrict__ out_z)
{
    __shared__ __align__(16) short T_sh[32 * TS];     // 16.5 KB shared transpose buffer
    __shared__ float2 red_sh[4][32][2];               // 2 KB: 4 LN stat buffers

    const int tid  = threadIdx.x;
    const int w    = tid >> 6;                        // wave id: owns feats [w*128, w*128+128)
    const int lane = tid & 63;
    const int r = lane & 15, kg = lane >> 4;
    const int fb  = w * 128;                          // feature base
    const int fbn = w * 8;                            // frag-block base (16-col blocks)
    const long r0 = (long)blockIdx.x * 32;

    f32x4 acc[2][8];

    // ================= GEMM1: z @ W1 (+b1 as C-init), wave's 128-feat slice =================
#pragma unroll
    for (int ni = 0; ni < 8; ++ni) {
        float bb = b1[fb + ni * 16 + r];
        acc[0][ni] = (f32x4){bb, bb, bb, bb};
        acc[1][ni] = acc[0][ni];
    }
    {
        const float* z0  = z + (r0 + r) * 256 + kg * 8;
        const float* z1r = z + (r0 + 16 + r) * 256 + kg * 8;
        float4 p00 = ((const float4*)z0)[0],  p01 = ((const float4*)z0)[1];
        float4 p10 = ((const float4*)z1r)[0], p11 = ((const float4*)z1r)[1];
        s16x8 bA[4], bB[4];
#pragma unroll
        for (int ni = 0; ni < 4; ++ni) bA[ni] = Wp1[(fbn + ni) * 64 + lane];
#pragma unroll
        for (int ni = 0; ni < 4; ++ni) bB[ni] = Wp1[(fbn + 4 + ni) * 64 + lane];
#pragma unroll
        for (int ks = 0; ks < 8; ++ks) {
            s16x8 a0 = cvt8(p00, p01);
            s16x8 a1 = cvt8(p10, p11);
            if (ks < 7) {
                p00 = ((const float4*)(z0 + (ks + 1) * 32))[0];
                p01 = ((const float4*)(z0 + (ks + 1) * 32))[1];
                p10 = ((const float4*)(z1r + (ks + 1) * 32))[0];
                p11 = ((const float4*)(z1r + (ks + 1) * 32))[1];
            }
#pragma unroll
            for (int ni = 0; ni < 4; ++ni) {
                acc[0][ni] = MFMA(a0, bA[ni], acc[0][ni]);
                acc[1][ni] = MFMA(a1, bA[ni], acc[1][ni]);
            }
            if (ks < 7) {
#pragma unroll
                for (int ni = 0; ni < 4; ++ni) bA[ni] = Wp1[((ks + 1) * 16 + fbn + ni) * 64 + lane];
            }
#pragma unroll
            for (int ni = 0; ni < 4; ++ni) {
                acc[0][4 + ni] = MFMA(a0, bB[ni], acc[0][4 + ni]);
                acc[1][4 + ni] = MFMA(a1, bB[ni], acc[1][4 + ni]);
            }
            if (ks < 7) {
#pragma unroll
                for (int ni = 0; ni < 4; ++ni) bB[ni] = Wp1[((ks + 1) * 16 + fbn + 4 + ni) * 64 + lane];
            }
        }
    }

    // relu + LN1 -> z1
#pragma unroll
    for (int mi = 0; mi < 2; ++mi)
#pragma unroll
        for (int ni = 0; ni < 8; ++ni)
#pragma unroll
            for (int j = 0; j < 4; ++j) acc[mi][ni][j] = fmaxf(acc[mi][ni][j], 0.f);
    ln_cw(acc, g_ln1, b_ln1, red_sh[0], r, kg, w, fb);

    // stage z1 (bf16) into shared T_sh: this wave's 128-feat slice, all 32 rows
#pragma unroll
    for (int mi = 0; mi < 2; ++mi)
#pragma unroll
        for (int j = 0; j < 4; ++j) {
            int row = mi * 16 + kg * 4 + j;
#pragma unroll
            for (int ni = 0; ni < 8; ++ni)
                T_sh[row * TS + fb + ni * 16 + r] = f2bf(acc[mi][ni][j]);
        }

    // ================= x-GEMM: x @ W_inp (+b_inp as C-init); x loaded at use =================
#pragma unroll
    for (int ni = 0; ni < 8; ++ni) {
        float bb = b_inp[fb + ni * 16 + r];
        acc[0][ni] = (f32x4){bb, bb, bb, bb};
        acc[1][ni] = acc[0][ni];
    }
    {
        const float* x0 = x + (r0 + r) * 48;
        const float* x1 = x + (r0 + 16 + r) * 48;
        float4 xa = ((const float4*)(x0 + kg * 8))[0];
        float4 xb = ((const float4*)(x0 + kg * 8))[1];
        float4 xc = ((const float4*)(x1 + kg * 8))[0];
        float4 xd = ((const float4*)(x1 + kg * 8))[1];
        float4 xe, xf, xg, xh;
        if (kg < 2) {
            xe = ((const float4*)(x0 + 32 + kg * 8))[0];
            xf = ((const float4*)(x0 + 32 + kg * 8))[1];
            xg = ((const float4*)(x1 + 32 + kg * 8))[0];
            xh = ((const float4*)(x1 + 32 + kg * 8))[1];
        } else {
            xe = xf = xg = xh = (float4){0.f, 0.f, 0.f, 0.f};
        }
        s16x8 a00 = cvt8(xa, xb);
        s16x8 a10 = cvt8(xc, xd);
        s16x8 a01 = cvt8(xe, xf);
        s16x8 a11 = cvt8(xg, xh);
#pragma unroll
        for (int ni = 0; ni < 8; ++ni) {
            s16x8 b = WpI[(fbn + ni) * 64 + lane];
            acc[0][ni] = MFMA(a00, b, acc[0][ni]);
            acc[1][ni] = MFMA(a10, b, acc[1][ni]);
        }
#pragma unroll
        for (int ni = 0; ni < 8; ++ni) {
            s16x8 b = WpI[(16 + fbn + ni) * 64 + lane];
            acc[0][ni] = MFMA(a01, b, acc[0][ni]);
            acc[1][ni] = MFMA(a11, b, acc[1][ni]);
        }
    }
    // LN_inp (its barrier also orders z1 staging before GEMM2's reads)
    ln_cw(acc, g_lni, b_lni, red_sh[1], r, kg, w, fb);   // acc = xinp

    // + b2 (C-init for GEMM2)
#pragma unroll
    for (int ni = 0; ni < 8; ++ni) {
        float bb = b2[fb + ni * 16 + r];
#pragma unroll
        for (int mi = 0; mi < 2; ++mi)
#pragma unroll
            for (int j = 0; j < 4; ++j) acc[mi][ni][j] += bb;
    }

    // ================= GEMM2: + z1 @ W2 (A-frags from shared T_sh, full K=256) =================
    {
        const char* Tb = (const char*)T_sh;
        s16x8 bA[4], bB[4];
#pragma unroll
        for (int ni = 0; ni < 4; ++ni) bA[ni] = Wp2[(fbn + ni) * 64 + lane];
#pragma unroll
        for (int ni = 0; ni < 4; ++ni) bB[ni] = Wp2[(fbn + 4 + ni) * 64 + lane];
#pragma unroll
        for (int ks = 0; ks < 8; ++ks) {
            int off = r * (TS * 2) + ks * 64 + kg * 16;
            s16x8 a0 = *(const s16x8*)(Tb + off);
            s16x8 a1 = *(const s16x8*)(Tb + off + 16 * TS * 2);
#pragma unroll
            for (int ni = 0; ni < 4; ++ni) {
                acc[0][ni] = MFMA(a0, bA[ni], acc[0][ni]);
                acc[1][ni] = MFMA(a1, bA[ni], acc[1][ni]);
            }
            if (ks < 7) {
#pragma unroll
                for (int ni = 0; ni < 4; ++ni) bA[ni] = Wp2[((ks + 1) * 16 + fbn + ni) * 64 + lane];
            }
#pragma unroll
            for (int ni = 0; ni < 4; ++ni) {
                acc[0][4 + ni] = MFMA(a0, bB[ni], acc[0][4 + ni]);
                acc[1][4 + ni] = MFMA(a1, bB[ni], acc[1][4 + ni]);
            }
            if (ks < 7) {
#pragma unroll
                for (int ni = 0; ni < 4; ++ni) bB[ni] = Wp2[((ks + 1) * 16 + fbn + 4 + ni) * 64 + lane];
            }
        }
    }
    ln_cw(acc, g_ln2, b_ln2, red_sh[2], r, kg, w, fb);   // acc = inner

    // ---- z_out = LN3(relu(z1 + inner)); z1 re-read from T_sh (own wave's slice, still intact) ----
#pragma unroll
    for (int mi = 0; mi < 2; ++mi)
#pragma unroll
        for (int j = 0; j < 4; ++j) {
            int row = mi * 16 + kg * 4 + j;
#pragma unroll
            for (int ni = 0; ni < 8; ++ni) {
                u32 v = *(const unsigned short*)&T_sh[row * TS + fb + ni * 16 + r];
                acc[mi][ni][j] = fmaxf(acc[mi][ni][j] + bf2f(v), 0.f);
            }
        }
    ln_cw(acc, g_ln3, b_ln3, red_sh[3], r, kg, w, fb);   // acc = z_out

    // stage z_out (bf16) into T_sh (overwrites z1; safe: both waves passed LN2/LN3 barriers)
#pragma unroll
    for (int mi = 0; mi < 2; ++mi)
#pragma unroll
        for (int j = 0; j < 4; ++j) {
            int row = mi * 16 + kg * 4 + j;
#pragma unroll
            for (int ni = 0; ni < 8; ++ni)
                T_sh[row * TS + fb + ni * 16 + r] = f2bf(acc[mi][ni][j]);
        }
    __syncthreads();

    // ================= out-GEMM: dx = z_out @ W_out (+b_out); wave w does cols [w*16, w*16+16) ====
    f32x4 ao[2];
    {
        float bb = b_out[w * 16 + r];
        ao[0] = (f32x4){bb, bb, bb, bb};
        ao[1] = ao[0];
    }
    {
        const char* Tb = (const char*)T_sh;
#pragma unroll
        for (int ks = 0; ks < 8; ++ks) {
            int off = r * (TS * 2) + ks * 64 + kg * 16;
            s16x8 a0 = *(const s16x8*)(Tb + off);
            s16x8 a1 = *(const s16x8*)(Tb + off + 16 * TS * 2);
            s16x8 b = WpO[(ks * 2 + w) * 64 + lane];
            ao[0] = MFMA(a0, b, ao[0]);
            ao[1] = MFMA(a1, b, ao[1]);
        }
    }
#pragma unroll
    for (int mi = 0; mi < 2; ++mi)
#pragma unroll
        for (int j = 0; j < 4; ++j)
            out_dx[(r0 + mi * 16 + kg * 4 + j) * 32 + w * 16 + r] = ao[mi][j];

    // ---- coalesced out_z copy: T_sh bf16 -> global f32; wave w copies rows [w*16, w*16+16) ----
    {
        float* zo = out_z + r0 * 256;
        const char* Tb = (const char*)T_sh;
#pragma unroll
        for (int it = 0; it < 8; ++it) {
            int row = w * 16 + it * 2 + (lane >> 5);
            int cs = (lane & 31) * 8;                       // col in shorts
            int4 wd = *(const int4*)(Tb + row * (TS * 2) + cs * 2);
            float4 o0, o1;
            o0.x = bf2f((u32)wd.x & 0xffffu); o0.y = bf2f((u32)wd.x >> 16);
            o0.z = bf2f((u32)wd.y & 0xffffu); o0.w = bf2f((u32)wd.y >> 16);
            o1.x = bf2f((u32)wd.z & 0xffffu); o1.y = bf2f((u32)wd.z >> 16);
            o1.z = bf2f((u32)wd.w & 0xffffu); o1.w = bf2f((u32)wd.w >> 16);
            *(float4*)(zo + row * 256 + cs) = o0;
            *(float4*)(zo + row * 256 + cs + 4) = o1;
        }
    }
}

extern "C" void kernel_launch(void* const* d_in, const int* in_sizes, int n_in,
                              void* d_out, int out_size, void* d_ws, size_t ws_size,
                              hipStream_t stream) {
    const float* x      = (const float*)d_in[0];
    const float* z      = (const float*)d_in[1];
    const float* W_inp  = (const float*)d_in[2];
    const float* b_inp  = (const float*)d_in[3];
    const float* g_lni  = (const float*)d_in[4];
    const float* b_lni  = (const float*)d_in[5];
    const float* W1     = (const float*)d_in[6];
    const float* b1     = (const float*)d_in[7];
    const float* g_ln1  = (const float*)d_in[8];
    const float* b_ln1  = (const float*)d_in[9];
    const float* W2     = (const float*)d_in[10];
    const float* b2     = (const float*)d_in[11];
    const float* g_ln2  = (const float*)d_in[12];
    const float* b_ln2  = (const float*)d_in[13];
    const float* g_ln3  = (const float*)d_in[14];
    const float* b_ln3  = (const float*)d_in[15];
    const float* W_out  = (const float*)d_in[16];
    const float* b_out  = (const float*)d_in[17];

    short* Wp1 = (short*)d_ws;            // 8*16*64*8  = 65536 bf16
    short* Wp2 = Wp1 + 65536;             // 65536
    short* WpI = Wp2 + 65536;             // 2*16*64*8  = 16384
    short* WpO = WpI + 16384;             // 8*2*64*8   = 8192

    pack_w<<<256, 256, 0, stream>>>(W1,    Wp1, 256, 256, 16, 65536);
    pack_w<<<256, 256, 0, stream>>>(W2,    Wp2, 256, 256, 16, 65536);
    pack_w<<< 64, 256, 0, stream>>>(W_inp, WpI,  48, 256, 16, 16384);
    pack_w<<< 32, 256, 0, stream>>>(W_out, WpO, 256,  32,  2,  8192);

    const long B = 262144;
    float* out_dx = (float*)d_out;
    float* out_z  = out_dx + B * 32;
    deq_main<<<B / 32, 128, 0, stream>>>(x, z, b_inp, g_lni, b_lni,
                                         b1, g_ln1, b_ln1, b2, g_ln2, b_ln2,
                                         g_ln3, b_ln3, b_out,
                                         (const s16x8*)Wp1, (const s16x8*)Wp2,
                                         (const s16x8*)WpI, (const s16x8*)WpO,
                                         out_dx, out_z);
}

// Round 8
// 404.436 us; speedup vs baseline: 2.3794x; 1.0082x over previous
//
#include <hip/hip_runtime.h>
#include <hip/hip_bf16.h>

typedef float f32x4 __attribute__((ext_vector_type(4)));
typedef short s16x8 __attribute__((ext_vector_type(8)));
typedef unsigned int u32;

__device__ __forceinline__ short f2bf(float f) {
    union { float f; u32 u; } c; c.f = f;
    return (short)((c.u + 0x8000u) >> 16);
}
__device__ __forceinline__ float bf2f(u32 v) {
    union { u32 u; float f; } c; c.u = v << 16; return c.f;
}
// HW packed f32->bf16 (RNE). No builtin on gfx950; inline asm per guide T12.
__device__ __forceinline__ u32 cvtpk(float lo, float hi) {
    u32 r;
    asm("v_cvt_pk_bf16_f32 %0, %1, %2" : "=v"(r) : "v"(lo), "v"(hi));
    return r;
}
__device__ __forceinline__ s16x8 cvt8(float4 f0, float4 f1) {
    union { s16x8 v; u32 w[4]; } u;
    u.w[0] = cvtpk(f0.x, f0.y); u.w[1] = cvtpk(f0.z, f0.w);
    u.w[2] = cvtpk(f1.x, f1.y); u.w[3] = cvtpk(f1.z, f1.w);
    return u.v;
}

// ---------------- weight packing: MFMA B-fragment order ----------------
__global__ void pack_w(const float* __restrict__ W, short* __restrict__ out,
                       int Kreal, int N, int nbTot, int total) {
    int tid = blockIdx.x * 256 + threadIdx.x;
    if (tid >= total) return;
    int j  = tid & 7;
    int l  = (tid >> 3) & 63;
    int blk = tid >> 9;            // ks*nbTot + nb
    int nb = blk % nbTot, ks = blk / nbTot;
    int k = ks * 32 + (l >> 4) * 8 + j;
    int n = nb * 16 + (l & 15);
    out[tid] = (k < Kreal) ? f2bf(W[(long)k * N + n]) : (short)0;
}

#define MFMA(a, b, c) __builtin_amdgcn_mfma_f32_16x16x32_bf16((a), (b), (c), 0, 0, 0)
#define TS 264   // T_sh row stride in shorts: 528 B = 33*16 B (16B-aligned, bank-rotating)

// ---------------- cross-wave layernorm over 256 feats (each wave owns 64) ----------------
// acc[mi][ni][j]: batch row = mi*16 + kg*4 + j, feat = fb + ni*16 + r.
__device__ __forceinline__ void ln_cw(f32x4 (&acc)[2][4], const float* __restrict__ g,
                                      const float* __restrict__ bl,
                                      float2 (*red)[4], int r, int kg, int w, int fb) {
#pragma unroll
    for (int mi = 0; mi < 2; ++mi)
#pragma unroll
        for (int j = 0; j < 4; ++j) {
            float s = 0.f, q = 0.f;
#pragma unroll
            for (int ni = 0; ni < 4; ++ni) { float v = acc[mi][ni][j]; s += v; q += v * v; }
#pragma unroll
            for (int m = 1; m < 16; m <<= 1) { s += __shfl_xor(s, m, 64); q += __shfl_xor(q, m, 64); }
            if (r == 0) red[mi * 16 + kg * 4 + j][w] = make_float2(s, q);
        }
    __syncthreads();
#pragma unroll
    for (int mi = 0; mi < 2; ++mi)
#pragma unroll
        for (int j = 0; j < 4; ++j) {
            int row = mi * 16 + kg * 4 + j;
            float2 p0 = red[row][0], p1 = red[row][1], p2 = red[row][2], p3 = red[row][3];
            float s = (p0.x + p1.x) + (p2.x + p3.x);
            float q = (p0.y + p1.y) + (p2.y + p3.y);
            float mean = s * (1.f / 256.f);
            float var  = fmaxf(q * (1.f / 256.f) - mean * mean, 0.f);
            float rstd = rsqrtf(var + 1e-5f);
#pragma unroll
            for (int ni = 0; ni < 4; ++ni)
                acc[mi][ni][j] = (acc[mi][ni][j] - mean) * rstd;
        }
#pragma unroll
    for (int ni = 0; ni < 4; ++ni) {
        float gg = g[fb + ni * 16 + r], bb = bl[fb + ni * 16 + r];
#pragma unroll
        for (int mi = 0; mi < 2; ++mi)
#pragma unroll
            for (int j = 0; j < 4; ++j) acc[mi][ni][j] = acc[mi][ni][j] * gg + bb;
    }
}

// ---------------- main fused kernel: 4 waves per block, 32 rows, 4-way feat-split ----------------
__global__ __launch_bounds__(256, 4) void deq_main(
    const float* __restrict__ x, const float* __restrict__ z,
    const float* __restrict__ b_inp, const float* __restrict__ g_lni, const float* __restrict__ b_lni,
    const float* __restrict__ b1, const float* __restrict__ g_ln1, const float* __restrict__ b_ln1,
    const float* __restrict__ b2, const float* __restrict__ g_ln2, const float* __restrict__ b_ln2,
    const float* __restrict__ g_ln3, const float* __restrict__ b_ln3,
    const float* __restrict__ b_out,
    const s16x8* __restrict__ Wp1, const s16x8* __restrict__ Wp2,
    const s16x8* __restrict__ WpI, const s16x8* __restrict__ WpO,
    float* __restrict__ out_dx, float* __restrict__ out_z)
{
    __shared__ __align__(16) short T_sh[32 * TS];     // 16.5 KB shared transpose buffer
    __shared__ float2 red_sh[4][32][4];               // 4 KB: 4 LN stat buffers x 4 waves

    const int tid  = threadIdx.x;
    const int w    = tid >> 6;                        // wave id: owns feats [w*64, w*64+64)
    const int lane = tid & 63;
    const int r = lane & 15, kg = lane >> 4;
    const int fb  = w * 64;                           // feature base
    const int fbn = w * 4;                            // frag-block base (16-col blocks)
    const long r0 = (long)blockIdx.x * 32;

    f32x4 acc[2][4];

    // ================= GEMM1: z @ W1 (+b1 as C-init), wave's 64-feat slice =================
#pragma unroll
    for (int ni = 0; ni < 4; ++ni) {
        float bb = b1[fb + ni * 16 + r];
        acc[0][ni] = (f32x4){bb, bb, bb, bb};
        acc[1][ni] = acc[0][ni];
    }
    {
        const float* z0  = z + (r0 + r) * 256 + kg * 8;
        const float* z1r = z + (r0 + 16 + r) * 256 + kg * 8;
        float4 p00 = ((const float4*)z0)[0],  p01 = ((const float4*)z0)[1];
        float4 p10 = ((const float4*)z1r)[0], p11 = ((const float4*)z1r)[1];
        s16x8 cur[4], nxt[4];
#pragma unroll
        for (int ni = 0; ni < 4; ++ni) cur[ni] = Wp1[(fbn + ni) * 64 + lane];
#pragma unroll
        for (int ks = 0; ks < 8; ++ks) {
            if (ks < 7) {
#pragma unroll
                for (int ni = 0; ni < 4; ++ni) nxt[ni] = Wp1[((ks + 1) * 16 + fbn + ni) * 64 + lane];
            }
            s16x8 a0 = cvt8(p00, p01);
            s16x8 a1 = cvt8(p10, p11);
            if (ks < 7) {
                p00 = ((const float4*)(z0 + (ks + 1) * 32))[0];
                p01 = ((const float4*)(z0 + (ks + 1) * 32))[1];
                p10 = ((const float4*)(z1r + (ks + 1) * 32))[0];
                p11 = ((const float4*)(z1r + (ks + 1) * 32))[1];
            }
#pragma unroll
            for (int ni = 0; ni < 4; ++ni) {
                acc[0][ni] = MFMA(a0, cur[ni], acc[0][ni]);
                acc[1][ni] = MFMA(a1, cur[ni], acc[1][ni]);
            }
#pragma unroll
            for (int ni = 0; ni < 4; ++ni) cur[ni] = nxt[ni];
        }
    }

    // relu + LN1 -> z1
#pragma unroll
    for (int mi = 0; mi < 2; ++mi)
#pragma unroll
        for (int ni = 0; ni < 4; ++ni)
#pragma unroll
            for (int j = 0; j < 4; ++j) acc[mi][ni][j] = fmaxf(acc[mi][ni][j], 0.f);
    ln_cw(acc, g_ln1, b_ln1, red_sh[0], r, kg, w, fb);

    // pack z1 (registers: residual copy) + stage bf16 into shared T_sh
    u32 z1p[2][4][2];
#pragma unroll
    for (int mi = 0; mi < 2; ++mi)
#pragma unroll
        for (int ni = 0; ni < 4; ++ni) {
            z1p[mi][ni][0] = cvtpk(acc[mi][ni][0], acc[mi][ni][1]);
            z1p[mi][ni][1] = cvtpk(acc[mi][ni][2], acc[mi][ni][3]);
        }
#pragma unroll
    for (int mi = 0; mi < 2; ++mi)
#pragma unroll
        for (int j = 0; j < 4; ++j) {
            int row = mi * 16 + kg * 4 + j;
#pragma unroll
            for (int ni = 0; ni < 4; ++ni)
                T_sh[row * TS + fb + ni * 16 + r] =
                    (short)(z1p[mi][ni][j >> 1] >> ((j & 1) * 16));
        }

    // ================= x-GEMM: x @ W_inp (+b_inp as C-init); x loaded at use =================
#pragma unroll
    for (int ni = 0; ni < 4; ++ni) {
        float bb = b_inp[fb + ni * 16 + r];
        acc[0][ni] = (f32x4){bb, bb, bb, bb};
        acc[1][ni] = acc[0][ni];
    }
    {
        const float* x0 = x + (r0 + r) * 48;
        const float* x1 = x + (r0 + 16 + r) * 48;
        float4 xa = ((const float4*)(x0 + kg * 8))[0];
        float4 xb = ((const float4*)(x0 + kg * 8))[1];
        float4 xc = ((const float4*)(x1 + kg * 8))[0];
        float4 xd = ((const float4*)(x1 + kg * 8))[1];
        float4 xe, xf, xg, xh;
        if (kg < 2) {
            xe = ((const float4*)(x0 + 32 + kg * 8))[0];
            xf = ((const float4*)(x0 + 32 + kg * 8))[1];
            xg = ((const float4*)(x1 + 32 + kg * 8))[0];
            xh = ((const float4*)(x1 + 32 + kg * 8))[1];
        } else {
            xe = xf = xg = xh = (float4){0.f, 0.f, 0.f, 0.f};
        }
        s16x8 a00 = cvt8(xa, xb);
        s16x8 a10 = cvt8(xc, xd);
        s16x8 a01 = cvt8(xe, xf);
        s16x8 a11 = cvt8(xg, xh);
#pragma unroll
        for (int ni = 0; ni < 4; ++ni) {
            s16x8 b = WpI[(fbn + ni) * 64 + lane];
            acc[0][ni] = MFMA(a00, b, acc[0][ni]);
            acc[1][ni] = MFMA(a10, b, acc[1][ni]);
        }
#pragma unroll
        for (int ni = 0; ni < 4; ++ni) {
            s16x8 b = WpI[(16 + fbn + ni) * 64 + lane];
            acc[0][ni] = MFMA(a01, b, acc[0][ni]);
            acc[1][ni] = MFMA(a11, b, acc[1][ni]);
        }
    }
    // LN_inp (its barrier also orders z1 staging before GEMM2's reads)
    ln_cw(acc, g_lni, b_lni, red_sh[1], r, kg, w, fb);   // acc = xinp

    // + b2 (C-init for GEMM2)
#pragma unroll
    for (int ni = 0; ni < 4; ++ni) {
        float bb = b2[fb + ni * 16 + r];
#pragma unroll
        for (int mi = 0; mi < 2; ++mi)
#pragma unroll
            for (int j = 0; j < 4; ++j) acc[mi][ni][j] += bb;
    }

    // ================= GEMM2: + z1 @ W2 (A-frags from shared T_sh, full K=256) =================
    {
        const char* Tb = (const char*)T_sh;
        s16x8 cur[4], nxt[4];
#pragma unroll
        for (int ni = 0; ni < 4; ++ni) cur[ni] = Wp2[(fbn + ni) * 64 + lane];
#pragma unroll
        for (int ks = 0; ks < 8; ++ks) {
            if (ks < 7) {
#pragma unroll
                for (int ni = 0; ni < 4; ++ni) nxt[ni] = Wp2[((ks + 1) * 16 + fbn + ni) * 64 + lane];
            }
            int off = r * (TS * 2) + ks * 64 + kg * 16;
            s16x8 a0 = *(const s16x8*)(Tb + off);
            s16x8 a1 = *(const s16x8*)(Tb + off + 16 * TS * 2);
#pragma unroll
            for (int ni = 0; ni < 4; ++ni) {
                acc[0][ni] = MFMA(a0, cur[ni], acc[0][ni]);
                acc[1][ni] = MFMA(a1, cur[ni], acc[1][ni]);
            }
#pragma unroll
            for (int ni = 0; ni < 4; ++ni) cur[ni] = nxt[ni];
        }
    }
    ln_cw(acc, g_ln2, b_ln2, red_sh[2], r, kg, w, fb);   // acc = inner

    // ---- z_out = LN3(relu(z1 + inner)); z1 from registers ----
#pragma unroll
    for (int mi = 0; mi < 2; ++mi)
#pragma unroll
        for (int ni = 0; ni < 4; ++ni) {
            acc[mi][ni][0] = fmaxf(acc[mi][ni][0] + bf2f(z1p[mi][ni][0] & 0xffffu), 0.f);
            acc[mi][ni][1] = fmaxf(acc[mi][ni][1] + bf2f(z1p[mi][ni][0] >> 16), 0.f);
            acc[mi][ni][2] = fmaxf(acc[mi][ni][2] + bf2f(z1p[mi][ni][1] & 0xffffu), 0.f);
            acc[mi][ni][3] = fmaxf(acc[mi][ni][3] + bf2f(z1p[mi][ni][1] >> 16), 0.f);
        }
    ln_cw(acc, g_ln3, b_ln3, red_sh[3], r, kg, w, fb);   // acc = z_out

    // stage z_out (bf16) into T_sh (overwrites z1; safe: all waves passed LN2/LN3 barriers)
#pragma unroll
    for (int mi = 0; mi < 2; ++mi)
#pragma unroll
        for (int ni = 0; ni < 4; ++ni) {
            u32 w0 = cvtpk(acc[mi][ni][0], acc[mi][ni][1]);
            u32 w1 = cvtpk(acc[mi][ni][2], acc[mi][ni][3]);
#pragma unroll
            for (int j = 0; j < 4; ++j) {
                int row = mi * 16 + kg * 4 + j;
                T_sh[row * TS + fb + ni * 16 + r] =
                    (short)(((j >> 1) ? w1 : w0) >> ((j & 1) * 16));
            }
        }
    __syncthreads();

    // ======= out-GEMM: dx = z_out @ W_out (+b_out); wave w -> (mi = w&1, nb = w>>1) =======
    {
        const int mi = w & 1, nb = w >> 1;
        float bb = b_out[nb * 16 + r];
        f32x4 ao = (f32x4){bb, bb, bb, bb};
        const char* Tb = (const char*)T_sh;
#pragma unroll
        for (int ks = 0; ks < 8; ++ks) {
            int off = (mi * 16 + r) * (TS * 2) + ks * 64 + kg * 16;
            s16x8 a0 = *(const s16x8*)(Tb + off);
            s16x8 b = WpO[(ks * 2 + nb) * 64 + lane];
            ao = MFMA(a0, b, ao);
        }
#pragma unroll
        for (int j = 0; j < 4; ++j)
            out_dx[(r0 + mi * 16 + kg * 4 + j) * 32 + nb * 16 + r] = ao[j];
    }

    // ---- coalesced out_z copy: T_sh bf16 -> global f32; wave w copies rows [w*8, w*8+8) ----
    {
        float* zo = out_z + r0 * 256;
        const char* Tb = (const char*)T_sh;
#pragma unroll
        for (int it = 0; it < 4; ++it) {
            int row = w * 8 + it * 2 + (lane >> 5);
            int cs = (lane & 31) * 8;                       // col in shorts
            int4 wd = *(const int4*)(Tb + row * (TS * 2) + cs * 2);
            float4 o0, o1;
            o0.x = bf2f((u32)wd.x & 0xffffu); o0.y = bf2f((u32)wd.x >> 16);
            o0.z = bf2f((u32)wd.y & 0xffffu); o0.w = bf2f((u32)wd.y >> 16);
            o1.x = bf2f((u32)wd.z & 0xffffu); o1.y = bf2f((u32)wd.z >> 16);
            o1.z = bf2f((u32)wd.w & 0xffffu); o1.w = bf2f((u32)wd.w >> 16);
            *(float4*)(zo + row * 256 + cs) = o0;
            *(float4*)(zo + row * 256 + cs + 4) = o1;
        }
    }
}

extern "C" void kernel_launch(void* const* d_in, const int* in_sizes, int n_in,
                              void* d_out, int out_size, void* d_ws, size_t ws_size,
                              hipStream_t stream) {
    const float* x      = (const float*)d_in[0];
    const float* z      = (const float*)d_in[1];
    const float* W_inp  = (const float*)d_in[2];
    const float* b_inp  = (const float*)d_in[3];
    const float* g_lni  = (const float*)d_in[4];
    const float* b_lni  = (const float*)d_in[5];
    const float* W1     = (const float*)d_in[6];
    const float* b1     = (const float*)d_in[7];
    const float* g_ln1  = (const float*)d_in[8];
    const float* b_ln1  = (const float*)d_in[9];
    const float* W2     = (const float*)d_in[10];
    const float* b2     = (const float*)d_in[11];
    const float* g_ln2  = (const float*)d_in[12];
    const float* b_ln2  = (const float*)d_in[13];
    const float* g_ln3  = (const float*)d_in[14];
    const float* b_ln3  = (const float*)d_in[15];
    const float* W_out  = (const float*)d_in[16];
    const float* b_out  = (const float*)d_in[17];

    short* Wp1 = (short*)d_ws;            // 8*16*64*8  = 65536 bf16
    short* Wp2 = Wp1 + 65536;             // 65536
    short* WpI = Wp2 + 65536;             // 2*16*64*8  = 16384
    short* WpO = WpI + 16384;             // 8*2*64*8   = 8192

    pack_w<<<256, 256, 0, stream>>>(W1,    Wp1, 256, 256, 16, 65536);
    pack_w<<<256, 256, 0, stream>>>(W2,    Wp2, 256, 256, 16, 65536);
    pack_w<<< 64, 256, 0, stream>>>(W_inp, WpI,  48, 256, 16, 16384);
    pack_w<<< 32, 256, 0, stream>>>(W_out, WpO, 256,  32,  2,  8192);

    const long B = 262144;
    float* out_dx = (float*)d_out;
    float* out_z  = out_dx + B * 32;
    deq_main<<<B / 32, 256, 0, stream>>>(x, z, b_inp, g_lni, b_lni,
                                         b1, g_ln1, b_ln1, b2, g_ln2, b_ln2,
                                         g_ln3, b_ln3, b_out,
                                         (const s16x8*)Wp1, (const s16x8*)Wp2,
                                         (const s16x8*)WpI, (const s16x8*)WpO,
                                         out_dx, out_z);
}

// Round 9
// 389.465 us; speedup vs baseline: 2.4709x; 1.0384x over previous
//
#include <hip/hip_runtime.h>
#include <hip/hip_bf16.h>

typedef float f32x4 __attribute__((ext_vector_type(4)));
typedef short s16x8 __attribute__((ext_vector_type(8)));
typedef unsigned int u32;

__device__ __forceinline__ short f2bf(float f) {
    union { float f; u32 u; } c; c.f = f;
    return (short)((c.u + 0x8000u) >> 16);
}
__device__ __forceinline__ float bf2f(u32 v) {
    union { u32 u; float f; } c; c.u = v << 16; return c.f;
}
// HW packed f32->bf16 (RNE). No builtin on gfx950; inline asm per guide T12.
__device__ __forceinline__ u32 cvtpk(float lo, float hi) {
    u32 r;
    asm("v_cvt_pk_bf16_f32 %0, %1, %2" : "=v"(r) : "v"(lo), "v"(hi));
    return r;
}
__device__ __forceinline__ s16x8 cvt8(float4 f0, float4 f1) {
    union { s16x8 v; u32 w[4]; } u;
    u.w[0] = cvtpk(f0.x, f0.y); u.w[1] = cvtpk(f0.z, f0.w);
    u.w[2] = cvtpk(f1.x, f1.y); u.w[3] = cvtpk(f1.z, f1.w);
    return u.v;
}

// ---------------- weight packing: MFMA B-fragment order ----------------
__global__ void pack_w(const float* __restrict__ W, short* __restrict__ out,
                       int Kreal, int N, int nbTot, int total) {
    int tid = blockIdx.x * 256 + threadIdx.x;
    if (tid >= total) return;
    int j  = tid & 7;
    int l  = (tid >> 3) & 63;
    int blk = tid >> 9;            // ks*nbTot + nb
    int nb = blk % nbTot, ks = blk / nbTot;
    int k = ks * 32 + (l >> 4) * 8 + j;
    int n = nb * 16 + (l & 15);
    out[tid] = (k < Kreal) ? f2bf(W[(long)k * N + n]) : (short)0;
}

#define MFMA(a, b, c) __builtin_amdgcn_mfma_f32_16x16x32_bf16((a), (b), (c), 0, 0, 0)
#define TS 264   // T_sh row stride in shorts: 528 B = 33*16 B (16B-aligned, bank-rotating)

// ---------------- cross-wave layernorm over 256 feats (each wave owns 64) ----------------
// acc[mi][ni][j]: batch row = mi*16 + kg*4 + j, feat = fb + ni*16 + r.
__device__ __forceinline__ void ln_cw(f32x4 (&acc)[2][4], const float* __restrict__ g,
                                      const float* __restrict__ bl,
                                      float2 (*red)[4], int r, int kg, int w, int fb) {
#pragma unroll
    for (int mi = 0; mi < 2; ++mi)
#pragma unroll
        for (int j = 0; j < 4; ++j) {
            float s = 0.f, q = 0.f;
#pragma unroll
            for (int ni = 0; ni < 4; ++ni) { float v = acc[mi][ni][j]; s += v; q += v * v; }
#pragma unroll
            for (int m = 1; m < 16; m <<= 1) { s += __shfl_xor(s, m, 64); q += __shfl_xor(q, m, 64); }
            if (r == 0) red[mi * 16 + kg * 4 + j][w] = make_float2(s, q);
        }
    __syncthreads();
#pragma unroll
    for (int mi = 0; mi < 2; ++mi)
#pragma unroll
        for (int j = 0; j < 4; ++j) {
            int row = mi * 16 + kg * 4 + j;
            float2 p0 = red[row][0], p1 = red[row][1], p2 = red[row][2], p3 = red[row][3];
            float s = (p0.x + p1.x) + (p2.x + p3.x);
            float q = (p0.y + p1.y) + (p2.y + p3.y);
            float mean = s * (1.f / 256.f);
            float var  = fmaxf(q * (1.f / 256.f) - mean * mean, 0.f);
            float rstd = rsqrtf(var + 1e-5f);
#pragma unroll
            for (int ni = 0; ni < 4; ++ni)
                acc[mi][ni][j] = (acc[mi][ni][j] - mean) * rstd;
        }
#pragma unroll
    for (int ni = 0; ni < 4; ++ni) {
        float gg = g[fb + ni * 16 + r], bb = bl[fb + ni * 16 + r];
#pragma unroll
        for (int mi = 0; mi < 2; ++mi)
#pragma unroll
            for (int j = 0; j < 4; ++j) acc[mi][ni][j] = acc[mi][ni][j] * gg + bb;
    }
}

// ---------------- main fused kernel: 4 waves per block, 32 rows, 4-way feat-split ----------------
__global__ __launch_bounds__(256, 3) void deq_main(
    const float* __restrict__ x, const float* __restrict__ z,
    const float* __restrict__ b_inp, const float* __restrict__ g_lni, const float* __restrict__ b_lni,
    const float* __restrict__ b1, const float* __restrict__ g_ln1, const float* __restrict__ b_ln1,
    const float* __restrict__ b2, const float* __restrict__ g_ln2, const float* __restrict__ b_ln2,
    const float* __restrict__ g_ln3, const float* __restrict__ b_ln3,
    const float* __restrict__ b_out,
    const s16x8* __restrict__ Wp1, const s16x8* __restrict__ Wp2,
    const s16x8* __restrict__ WpI, const s16x8* __restrict__ WpO,
    float* __restrict__ out_dx, float* __restrict__ out_z)
{
    __shared__ __align__(16) short T_sh[32 * TS];     // 16.5 KB shared transpose buffer
    __shared__ float2 red_sh[4][32][4];               // 4 KB: 4 LN stat buffers x 4 waves

    const int tid  = threadIdx.x;
    const int w    = tid >> 6;                        // wave id: owns feats [w*64, w*64+64)
    const int lane = tid & 63;
    const int r = lane & 15, kg = lane >> 4;
    const int fb  = w * 64;                           // feature base
    const int fbn = w * 4;                            // frag-block base (16-col blocks)
    const long r0 = (long)blockIdx.x * 32;

    f32x4 acc[2][4];

    // ================= GEMM1: z @ W1 (+b1 as C-init), wave's 64-feat slice =================
    // z-load pipeline depth 4 (64 VGPR in flight) to cover ~900cy HBM latency.
#pragma unroll
    for (int ni = 0; ni < 4; ++ni) {
        float bb = b1[fb + ni * 16 + r];
        acc[0][ni] = (f32x4){bb, bb, bb, bb};
        acc[1][ni] = acc[0][ni];
    }
    {
        const float* z0  = z + (r0 + r) * 256 + kg * 8;
        const float* z1r = z + (r0 + 16 + r) * 256 + kg * 8;
        float4 zb[4][4];
#pragma unroll
        for (int s = 0; s < 4; ++s) {
            zb[s][0] = ((const float4*)(z0 + s * 32))[0];
            zb[s][1] = ((const float4*)(z0 + s * 32))[1];
            zb[s][2] = ((const float4*)(z1r + s * 32))[0];
            zb[s][3] = ((const float4*)(z1r + s * 32))[1];
        }
        s16x8 cur[4], nxt[4];
#pragma unroll
        for (int ni = 0; ni < 4; ++ni) cur[ni] = Wp1[(fbn + ni) * 64 + lane];
#pragma unroll
        for (int ks = 0; ks < 8; ++ks) {
            const int slot = ks & 3;
            if (ks < 7) {
#pragma unroll
                for (int ni = 0; ni < 4; ++ni) nxt[ni] = Wp1[((ks + 1) * 16 + fbn + ni) * 64 + lane];
            }
            s16x8 a0 = cvt8(zb[slot][0], zb[slot][1]);
            s16x8 a1 = cvt8(zb[slot][2], zb[slot][3]);
            if (ks < 4) {   // refill slot with ks+4's data
                zb[slot][0] = ((const float4*)(z0 + (ks + 4) * 32))[0];
                zb[slot][1] = ((const float4*)(z0 + (ks + 4) * 32))[1];
                zb[slot][2] = ((const float4*)(z1r + (ks + 4) * 32))[0];
                zb[slot][3] = ((const float4*)(z1r + (ks + 4) * 32))[1];
            }
#pragma unroll
            for (int ni = 0; ni < 4; ++ni) {
                acc[0][ni] = MFMA(a0, cur[ni], acc[0][ni]);
                acc[1][ni] = MFMA(a1, cur[ni], acc[1][ni]);
            }
#pragma unroll
            for (int ni = 0; ni < 4; ++ni) cur[ni] = nxt[ni];
        }
    }

    // issue x loads early: ~900cy HBM latency hides under relu+LN1+z1 staging
    float4 xv0, xv1, xv2, xv3, xv4, xv5, xv6, xv7;
    {
        const float* x0 = x + (r0 + r) * 48;
        const float* x1 = x + (r0 + 16 + r) * 48;
        xv0 = ((const float4*)(x0 + kg * 8))[0];
        xv1 = ((const float4*)(x0 + kg * 8))[1];
        xv2 = ((const float4*)(x1 + kg * 8))[0];
        xv3 = ((const float4*)(x1 + kg * 8))[1];
        if (kg < 2) {
            xv4 = ((const float4*)(x0 + 32 + kg * 8))[0];
            xv5 = ((const float4*)(x0 + 32 + kg * 8))[1];
            xv6 = ((const float4*)(x1 + 32 + kg * 8))[0];
            xv7 = ((const float4*)(x1 + 32 + kg * 8))[1];
        } else {
            xv4 = xv5 = xv6 = xv7 = (float4){0.f, 0.f, 0.f, 0.f};
        }
    }

    // relu + LN1 -> z1
#pragma unroll
    for (int mi = 0; mi < 2; ++mi)
#pragma unroll
        for (int ni = 0; ni < 4; ++ni)
#pragma unroll
            for (int j = 0; j < 4; ++j) acc[mi][ni][j] = fmaxf(acc[mi][ni][j], 0.f);
    ln_cw(acc, g_ln1, b_ln1, red_sh[0], r, kg, w, fb);

    // pack z1 (registers: residual copy) + stage bf16 into shared T_sh
    u32 z1p[2][4][2];
#pragma unroll
    for (int mi = 0; mi < 2; ++mi)
#pragma unroll
        for (int ni = 0; ni < 4; ++ni) {
            z1p[mi][ni][0] = cvtpk(acc[mi][ni][0], acc[mi][ni][1]);
            z1p[mi][ni][1] = cvtpk(acc[mi][ni][2], acc[mi][ni][3]);
        }
#pragma unroll
    for (int mi = 0; mi < 2; ++mi)
#pragma unroll
        for (int j = 0; j < 4; ++j) {
            int row = mi * 16 + kg * 4 + j;
#pragma unroll
            for (int ni = 0; ni < 4; ++ni)
                T_sh[row * TS + fb + ni * 16 + r] =
                    (short)(z1p[mi][ni][j >> 1] >> ((j & 1) * 16));
        }

    // ================= x-GEMM: x @ W_inp (+b_inp as C-init) =================
#pragma unroll
    for (int ni = 0; ni < 4; ++ni) {
        float bb = b_inp[fb + ni * 16 + r];
        acc[0][ni] = (f32x4){bb, bb, bb, bb};
        acc[1][ni] = acc[0][ni];
    }
    {
        s16x8 a00 = cvt8(xv0, xv1);
        s16x8 a10 = cvt8(xv2, xv3);
        s16x8 a01 = cvt8(xv4, xv5);
        s16x8 a11 = cvt8(xv6, xv7);
#pragma unroll
        for (int ni = 0; ni < 4; ++ni) {
            s16x8 b = WpI[(fbn + ni) * 64 + lane];
            acc[0][ni] = MFMA(a00, b, acc[0][ni]);
            acc[1][ni] = MFMA(a10, b, acc[1][ni]);
        }
#pragma unroll
        for (int ni = 0; ni < 4; ++ni) {
            s16x8 b = WpI[(16 + fbn + ni) * 64 + lane];
            acc[0][ni] = MFMA(a01, b, acc[0][ni]);
            acc[1][ni] = MFMA(a11, b, acc[1][ni]);
        }
    }
    // LN_inp (its barrier also orders z1 staging before GEMM2's reads)
    ln_cw(acc, g_lni, b_lni, red_sh[1], r, kg, w, fb);   // acc = xinp

    // + b2 (C-init for GEMM2)
#pragma unroll
    for (int ni = 0; ni < 4; ++ni) {
        float bb = b2[fb + ni * 16 + r];
#pragma unroll
        for (int mi = 0; mi < 2; ++mi)
#pragma unroll
            for (int j = 0; j < 4; ++j) acc[mi][ni][j] += bb;
    }

    // ================= GEMM2: + z1 @ W2 (A-frags from shared T_sh, full K=256) =================
    {
        const char* Tb = (const char*)T_sh;
        s16x8 cur[4], nxt[4];
#pragma unroll
        for (int ni = 0; ni < 4; ++ni) cur[ni] = Wp2[(fbn + ni) * 64 + lane];
#pragma unroll
        for (int ks = 0; ks < 8; ++ks) {
            if (ks < 7) {
#pragma unroll
                for (int ni = 0; ni < 4; ++ni) nxt[ni] = Wp2[((ks + 1) * 16 + fbn + ni) * 64 + lane];
            }
            int off = r * (TS * 2) + ks * 64 + kg * 16;
            s16x8 a0 = *(const s16x8*)(Tb + off);
            s16x8 a1 = *(const s16x8*)(Tb + off + 16 * TS * 2);
#pragma unroll
            for (int ni = 0; ni < 4; ++ni) {
                acc[0][ni] = MFMA(a0, cur[ni], acc[0][ni]);
                acc[1][ni] = MFMA(a1, cur[ni], acc[1][ni]);
            }
#pragma unroll
            for (int ni = 0; ni < 4; ++ni) cur[ni] = nxt[ni];
        }
    }
    ln_cw(acc, g_ln2, b_ln2, red_sh[2], r, kg, w, fb);   // acc = inner

    // ---- z_out = LN3(relu(z1 + inner)); z1 from registers ----
#pragma unroll
    for (int mi = 0; mi < 2; ++mi)
#pragma unroll
        for (int ni = 0; ni < 4; ++ni) {
            acc[mi][ni][0] = fmaxf(acc[mi][ni][0] + bf2f(z1p[mi][ni][0] & 0xffffu), 0.f);
            acc[mi][ni][1] = fmaxf(acc[mi][ni][1] + bf2f(z1p[mi][ni][0] >> 16), 0.f);
            acc[mi][ni][2] = fmaxf(acc[mi][ni][2] + bf2f(z1p[mi][ni][1] & 0xffffu), 0.f);
            acc[mi][ni][3] = fmaxf(acc[mi][ni][3] + bf2f(z1p[mi][ni][1] >> 16), 0.f);
        }
    ln_cw(acc, g_ln3, b_ln3, red_sh[3], r, kg, w, fb);   // acc = z_out

    // stage z_out (bf16) into T_sh (overwrites z1; safe: all waves passed LN2/LN3 barriers)
#pragma unroll
    for (int mi = 0; mi < 2; ++mi)
#pragma unroll
        for (int ni = 0; ni < 4; ++ni) {
            u32 w0 = cvtpk(acc[mi][ni][0], acc[mi][ni][1]);
            u32 w1 = cvtpk(acc[mi][ni][2], acc[mi][ni][3]);
#pragma unroll
            for (int j = 0; j < 4; ++j) {
                int row = mi * 16 + kg * 4 + j;
                T_sh[row * TS + fb + ni * 16 + r] =
                    (short)(((j >> 1) ? w1 : w0) >> ((j & 1) * 16));
            }
        }
    __syncthreads();

    // ======= out-GEMM: dx = z_out @ W_out (+b_out); wave w -> (mi = w&1, nb = w>>1) =======
    {
        const int mi = w & 1, nb = w >> 1;
        float bb = b_out[nb * 16 + r];
        f32x4 ao = (f32x4){bb, bb, bb, bb};
        const char* Tb = (const char*)T_sh;
#pragma unroll
        for (int ks = 0; ks < 8; ++ks) {
            int off = (mi * 16 + r) * (TS * 2) + ks * 64 + kg * 16;
            s16x8 a0 = *(const s16x8*)(Tb + off);
            s16x8 b = WpO[(ks * 2 + nb) * 64 + lane];
            ao = MFMA(a0, b, ao);
        }
#pragma unroll
        for (int j = 0; j < 4; ++j)
            out_dx[(r0 + mi * 16 + kg * 4 + j) * 32 + nb * 16 + r] = ao[j];
    }

    // ---- coalesced out_z copy: T_sh bf16 -> global f32; wave w copies rows [w*8, w*8+8) ----
    {
        float* zo = out_z + r0 * 256;
        const char* Tb = (const char*)T_sh;
#pragma unroll
        for (int it = 0; it < 4; ++it) {
            int row = w * 8 + it * 2 + (lane >> 5);
            int cs = (lane & 31) * 8;                       // col in shorts
            int4 wd = *(const int4*)(Tb + row * (TS * 2) + cs * 2);
            float4 o0, o1;
            o0.x = bf2f((u32)wd.x & 0xffffu); o0.y = bf2f((u32)wd.x >> 16);
            o0.z = bf2f((u32)wd.y & 0xffffu); o0.w = bf2f((u32)wd.y >> 16);
            o1.x = bf2f((u32)wd.z & 0xffffu); o1.y = bf2f((u32)wd.z >> 16);
            o1.z = bf2f((u32)wd.w & 0xffffu); o1.w = bf2f((u32)wd.w >> 16);
            *(float4*)(zo + row * 256 + cs) = o0;
            *(float4*)(zo + row * 256 + cs + 4) = o1;
        }
    }
}

extern "C" void kernel_launch(void* const* d_in, const int* in_sizes, int n_in,
                              void* d_out, int out_size, void* d_ws, size_t ws_size,
                              hipStream_t stream) {
    const float* x      = (const float*)d_in[0];
    const float* z      = (const float*)d_in[1];
    const float* W_inp  = (const float*)d_in[2];
    const float* b_inp  = (const float*)d_in[3];
    const float* g_lni  = (const float*)d_in[4];
    const float* b_lni  = (const float*)d_in[5];
    const float* W1     = (const float*)d_in[6];
    const float* b1     = (const float*)d_in[7];
    const float* g_ln1  = (const float*)d_in[8];
    const float* b_ln1  = (const float*)d_in[9];
    const float* W2     = (const float*)d_in[10];
    const float* b2     = (const float*)d_in[11];
    const float* g_ln2  = (const float*)d_in[12];
    const float* b_ln2  = (const float*)d_in[13];
    const float* g_ln3  = (const float*)d_in[14];
    const float* b_ln3  = (const float*)d_in[15];
    const float* W_out  = (const float*)d_in[16];
    const float* b_out  = (const float*)d_in[17];

    short* Wp1 = (short*)d_ws;            // 8*16*64*8  = 65536 bf16
    short* Wp2 = Wp1 + 65536;             // 65536
    short* WpI = Wp2 + 65536;             // 2*16*64*8  = 16384
    short* WpO = WpI + 16384;             // 8*2*64*8   = 8192

    pack_w<<<256, 256, 0, stream>>>(W1,    Wp1, 256, 256, 16, 65536);
    pack_w<<<256, 256, 0, stream>>>(W2,    Wp2, 256, 256, 16, 65536);
    pack_w<<< 64, 256, 0, stream>>>(W_inp, WpI,  48, 256, 16, 16384);
    pack_w<<< 32, 256, 0, stream>>>(W_out, WpO, 256,  32,  2,  8192);

    const long B = 262144;
    float* out_dx = (float*)d_out;
    float* out_z  = out_dx + B * 32;
    deq_main<<<B / 32, 256, 0, stream>>>(x, z, b_inp, g_lni, b_lni,
                                         b1, g_ln1, b_ln1, b2, g_ln2, b_ln2,
                                         g_ln3, b_ln3, b_out,
                                         (const s16x8*)Wp1, (const s16x8*)Wp2,
                                         (const s16x8*)WpI, (const s16x8*)WpO,
                                         out_dx, out_z);
}

// Round 10
// 369.670 us; speedup vs baseline: 2.6032x; 1.0535x over previous
//
#include <hip/hip_runtime.h>
#include <hip/hip_bf16.h>

typedef float f32x4 __attribute__((ext_vector_type(4)));
typedef short s16x8 __attribute__((ext_vector_type(8)));
typedef unsigned int u32;

__device__ __forceinline__ short f2bf(float f) {
    union { float f; u32 u; } c; c.f = f;
    return (short)((c.u + 0x8000u) >> 16);
}
__device__ __forceinline__ float bf2f(u32 v) {
    union { u32 u; float f; } c; c.u = v << 16; return c.f;
}
// HW packed f32->bf16 (RNE). No builtin on gfx950; inline asm per guide T12.
__device__ __forceinline__ u32 cvtpk(float lo, float hi) {
    u32 r;
    asm("v_cvt_pk_bf16_f32 %0, %1, %2" : "=v"(r) : "v"(lo), "v"(hi));
    return r;
}
__device__ __forceinline__ s16x8 cvt8(float4 f0, float4 f1) {
    union { s16x8 v; u32 w[4]; } u;
    u.w[0] = cvtpk(f0.x, f0.y); u.w[1] = cvtpk(f0.z, f0.w);
    u.w[2] = cvtpk(f1.x, f1.y); u.w[3] = cvtpk(f1.z, f1.w);
    return u.v;
}
__device__ __forceinline__ s16x8 cvt8v(f32x4 a, f32x4 b) {
    union { s16x8 v; u32 w[4]; } u;
    u.w[0] = cvtpk(a[0], a[1]); u.w[1] = cvtpk(a[2], a[3]);
    u.w[2] = cvtpk(b[0], b[1]); u.w[3] = cvtpk(b[2], b[3]);
    return u.v;
}
// async global->LDS DMA, 16B/lane; LDS dest = base + lane*16 (wave-uniform base)
__device__ __forceinline__ void gload16(const void* g, void* l) {
    __builtin_amdgcn_global_load_lds((const __attribute__((address_space(1))) u32*)g,
                                     (__attribute__((address_space(3))) u32*)l, 16, 0, 0);
}

// ---------------- weight packing: MFMA B-fragment order ----------------
__global__ void pack_w(const float* __restrict__ W, short* __restrict__ out,
                       int Kreal, int N, int nbTot, int total) {
    int tid = blockIdx.x * 256 + threadIdx.x;
    if (tid >= total) return;
    int j  = tid & 7;
    int l  = (tid >> 3) & 63;
    int blk = tid >> 9;            // ks*nbTot + nb
    int nb = blk % nbTot, ks = blk / nbTot;
    int k = ks * 32 + (l >> 4) * 8 + j;
    int n = nb * 16 + (l & 15);
    out[tid] = (k < Kreal) ? f2bf(W[(long)k * N + n]) : (short)0;
}

#define MFMA(a, b, c) __builtin_amdgcn_mfma_f32_16x16x32_bf16((a), (b), (c), 0, 0, 0)
#define TS 264   // T_sh row stride in shorts: 528 B = 33*16 B (16B-aligned, bank-rotating)

// ---------------- cross-wave layernorm over 256 feats (each wave owns 64) ----------------
// acc[mi][ni][j]: batch row = mi*16 + kg*4 + j, feat = fb + ni*16 + r.
__device__ __forceinline__ void ln_cw(f32x4 (&acc)[2][4], const float* __restrict__ g,
                                      const float* __restrict__ bl,
                                      float2* red, int r, int kg, int w, int fb) {
#pragma unroll
    for (int mi = 0; mi < 2; ++mi)
#pragma unroll
        for (int j = 0; j < 4; ++j) {
            float s = 0.f, q = 0.f;
#pragma unroll
            for (int ni = 0; ni < 4; ++ni) { float v = acc[mi][ni][j]; s += v; q += v * v; }
#pragma unroll
            for (int m = 1; m < 16; m <<= 1) { s += __shfl_xor(s, m, 64); q += __shfl_xor(q, m, 64); }
            if (r == 0) red[(mi * 16 + kg * 4 + j) * 4 + w] = make_float2(s, q);
        }
    __syncthreads();
#pragma unroll
    for (int mi = 0; mi < 2; ++mi)
#pragma unroll
        for (int j = 0; j < 4; ++j) {
            int row = mi * 16 + kg * 4 + j;
            float2 p0 = red[row * 4 + 0], p1 = red[row * 4 + 1];
            float2 p2 = red[row * 4 + 2], p3 = red[row * 4 + 3];
            float s = (p0.x + p1.x) + (p2.x + p3.x);
            float q = (p0.y + p1.y) + (p2.y + p3.y);
            float mean = s * (1.f / 256.f);
            float var  = fmaxf(q * (1.f / 256.f) - mean * mean, 0.f);
            float rstd = rsqrtf(var + 1e-5f);
#pragma unroll
            for (int ni = 0; ni < 4; ++ni)
                acc[mi][ni][j] = (acc[mi][ni][j] - mean) * rstd;
        }
#pragma unroll
    for (int ni = 0; ni < 4; ++ni) {
        float gg = g[fb + ni * 16 + r], bb = bl[fb + ni * 16 + r];
#pragma unroll
        for (int mi = 0; mi < 2; ++mi)
#pragma unroll
            for (int j = 0; j < 4; ++j) acc[mi][ni][j] = acc[mi][ni][j] * gg + bb;
    }
}

// ---------------- main fused kernel: 4 waves per block, 32 rows, 4-way feat-split ----------------
__global__ __launch_bounds__(256, 4) void deq_main(
    const float* __restrict__ x, const float* __restrict__ z,
    const float* __restrict__ b_inp, const float* __restrict__ g_lni, const float* __restrict__ b_lni,
    const float* __restrict__ b1, const float* __restrict__ g_ln1, const float* __restrict__ b_ln1,
    const float* __restrict__ b2, const float* __restrict__ g_ln2, const float* __restrict__ b_ln2,
    const float* __restrict__ g_ln3, const float* __restrict__ b_ln3,
    const float* __restrict__ b_out,
    const s16x8* __restrict__ Wp1, const s16x8* __restrict__ Wp2,
    const s16x8* __restrict__ WpI, const s16x8* __restrict__ WpO,
    float* __restrict__ out_dx, float* __restrict__ out_z)
{
    // 36 KB pool: [0,32K) = z-tile f32 (rows of 1KB, source-swizzled), later overlaid by
    // T_sh (16.5KB bf16 transpose buffer — z dead at LN1's barrier); [32K,36K) = LN stats.
    __shared__ __align__(16) char smem[36 * 1024];
    short*  T_sh = (short*)smem;
    float2* red  = (float2*)(smem + 32 * 1024);

    const int tid  = threadIdx.x;
    const int w    = tid >> 6;                        // wave id: owns feats [w*64, w*64+64)
    const int lane = tid & 63;
    const int r = lane & 15, kg = lane >> 4;
    const int fb  = w * 64;                           // feature base
    const int fbn = w * 4;                            // frag-block base (16-col blocks)
    const long r0 = (long)blockIdx.x * 32;
    const int swzr = (r & 7) << 4;

    // ---- async DMA: stage z tile (32 rows x 1KB) into LDS; wave w stages rows [w*8, w*8+8) ----
#pragma unroll
    for (int i = 0; i < 8; ++i) {
        int row = w * 8 + i;
        const char* gp = (const char*)(z + (r0 + row) * 256) + ((lane * 16) ^ ((row & 7) << 4));
        gload16(gp, smem + row * 1024);
    }

    // x loads to regs (complete under the staging barrier)
    float4 xv0, xv1, xv2, xv3, xv4, xv5, xv6, xv7;
    {
        const float* x0 = x + (r0 + r) * 48;
        const float* x1 = x + (r0 + 16 + r) * 48;
        xv0 = ((const float4*)(x0 + kg * 8))[0];
        xv1 = ((const float4*)(x0 + kg * 8))[1];
        xv2 = ((const float4*)(x1 + kg * 8))[0];
        xv3 = ((const float4*)(x1 + kg * 8))[1];
        if (kg < 2) {
            xv4 = ((const float4*)(x0 + 32 + kg * 8))[0];
            xv5 = ((const float4*)(x0 + 32 + kg * 8))[1];
            xv6 = ((const float4*)(x1 + 32 + kg * 8))[0];
            xv7 = ((const float4*)(x1 + 32 + kg * 8))[1];
        } else {
            xv4 = xv5 = xv6 = xv7 = (float4){0.f, 0.f, 0.f, 0.f};
        }
    }
    __syncthreads();   // drains DMA (compiler emits vmcnt(0) before s_barrier)

    f32x4 acc[2][4];

    // ================= GEMM1: z @ W1 (+b1 as C-init), A-frags from LDS =================
#pragma unroll
    for (int ni = 0; ni < 4; ++ni) {
        float bb = b1[fb + ni * 16 + r];
        acc[0][ni] = (f32x4){bb, bb, bb, bb};
        acc[1][ni] = acc[0][ni];
    }
    {
        const char* zl0 = smem + r * 1024;
        const char* zl1 = smem + (r + 16) * 1024;     // (r+16)&7 == r&7 -> same swizzle
        s16x8 cur[4], nxt[4];
#pragma unroll
        for (int ni = 0; ni < 4; ++ni) cur[ni] = Wp1[(fbn + ni) * 64 + lane];
#pragma unroll
        for (int ks = 0; ks < 8; ++ks) {
            if (ks < 7) {
#pragma unroll
                for (int ni = 0; ni < 4; ++ni) nxt[ni] = Wp1[((ks + 1) * 16 + fbn + ni) * 64 + lane];
            }
            const int c = ks * 128 + kg * 32;
            f32x4 a0lo = *(const f32x4*)(zl0 + ((c) ^ swzr));
            f32x4 a0hi = *(const f32x4*)(zl0 + ((c + 16) ^ swzr));
            f32x4 a1lo = *(const f32x4*)(zl1 + ((c) ^ swzr));
            f32x4 a1hi = *(const f32x4*)(zl1 + ((c + 16) ^ swzr));
            s16x8 a0 = cvt8v(a0lo, a0hi);
            s16x8 a1 = cvt8v(a1lo, a1hi);
#pragma unroll
            for (int ni = 0; ni < 4; ++ni) {
                acc[0][ni] = MFMA(a0, cur[ni], acc[0][ni]);
                acc[1][ni] = MFMA(a1, cur[ni], acc[1][ni]);
            }
#pragma unroll
            for (int ni = 0; ni < 4; ++ni) cur[ni] = nxt[ni];
        }
    }

    // relu + LN1 -> z1   (LN1's barrier: all waves done reading z -> safe to overlay T_sh)
#pragma unroll
    for (int mi = 0; mi < 2; ++mi)
#pragma unroll
        for (int ni = 0; ni < 4; ++ni)
#pragma unroll
            for (int j = 0; j < 4; ++j) acc[mi][ni][j] = fmaxf(acc[mi][ni][j], 0.f);
    ln_cw(acc, g_ln1, b_ln1, red + 0 * 128, r, kg, w, fb);

    // pack z1 (registers: residual copy) + stage bf16 into T_sh
    u32 z1p[2][4][2];
#pragma unroll
    for (int mi = 0; mi < 2; ++mi)
#pragma unroll
        for (int ni = 0; ni < 4; ++ni) {
            z1p[mi][ni][0] = cvtpk(acc[mi][ni][0], acc[mi][ni][1]);
            z1p[mi][ni][1] = cvtpk(acc[mi][ni][2], acc[mi][ni][3]);
        }
#pragma unroll
    for (int mi = 0; mi < 2; ++mi)
#pragma unroll
        for (int j = 0; j < 4; ++j) {
            int row = mi * 16 + kg * 4 + j;
#pragma unroll
            for (int ni = 0; ni < 4; ++ni)
                T_sh[row * TS + fb + ni * 16 + r] =
                    (short)(z1p[mi][ni][j >> 1] >> ((j & 1) * 16));
        }

    // ================= x-GEMM: x @ W_inp (+b_inp as C-init) =================
#pragma unroll
    for (int ni = 0; ni < 4; ++ni) {
        float bb = b_inp[fb + ni * 16 + r];
        acc[0][ni] = (f32x4){bb, bb, bb, bb};
        acc[1][ni] = acc[0][ni];
    }
    {
        s16x8 a00 = cvt8(xv0, xv1);
        s16x8 a10 = cvt8(xv2, xv3);
        s16x8 a01 = cvt8(xv4, xv5);
        s16x8 a11 = cvt8(xv6, xv7);
#pragma unroll
        for (int ni = 0; ni < 4; ++ni) {
            s16x8 b = WpI[(fbn + ni) * 64 + lane];
            acc[0][ni] = MFMA(a00, b, acc[0][ni]);
            acc[1][ni] = MFMA(a10, b, acc[1][ni]);
        }
#pragma unroll
        for (int ni = 0; ni < 4; ++ni) {
            s16x8 b = WpI[(16 + fbn + ni) * 64 + lane];
            acc[0][ni] = MFMA(a01, b, acc[0][ni]);
            acc[1][ni] = MFMA(a11, b, acc[1][ni]);
        }
    }
    // LN_inp (its barrier also orders z1 staging before GEMM2's reads)
    ln_cw(acc, g_lni, b_lni, red + 1 * 128, r, kg, w, fb);   // acc = xinp

    // + b2 (C-init for GEMM2)
#pragma unroll
    for (int ni = 0; ni < 4; ++ni) {
        float bb = b2[fb + ni * 16 + r];
#pragma unroll
        for (int mi = 0; mi < 2; ++mi)
#pragma unroll
            for (int j = 0; j < 4; ++j) acc[mi][ni][j] += bb;
    }

    // ================= GEMM2: + z1 @ W2 (A-frags from T_sh, full K=256) =================
    {
        const char* Tb = (const char*)T_sh;
        s16x8 cur[4], nxt[4];
#pragma unroll
        for (int ni = 0; ni < 4; ++ni) cur[ni] = Wp2[(fbn + ni) * 64 + lane];
#pragma unroll
        for (int ks = 0; ks < 8; ++ks) {
            if (ks < 7) {
#pragma unroll
                for (int ni = 0; ni < 4; ++ni) nxt[ni] = Wp2[((ks + 1) * 16 + fbn + ni) * 64 + lane];
            }
            int off = r * (TS * 2) + ks * 64 + kg * 16;
            s16x8 a0 = *(const s16x8*)(Tb + off);
            s16x8 a1 = *(const s16x8*)(Tb + off + 16 * TS * 2);
#pragma unroll
            for (int ni = 0; ni < 4; ++ni) {
                acc[0][ni] = MFMA(a0, cur[ni], acc[0][ni]);
                acc[1][ni] = MFMA(a1, cur[ni], acc[1][ni]);
            }
#pragma unroll
            for (int ni = 0; ni < 4; ++ni) cur[ni] = nxt[ni];
        }
    }
    ln_cw(acc, g_ln2, b_ln2, red + 2 * 128, r, kg, w, fb);   // acc = inner

    // ---- z_out = LN3(relu(z1 + inner)); z1 from registers ----
#pragma unroll
    for (int mi = 0; mi < 2; ++mi)
#pragma unroll
        for (int ni = 0; ni < 4; ++ni) {
            acc[mi][ni][0] = fmaxf(acc[mi][ni][0] + bf2f(z1p[mi][ni][0] & 0xffffu), 0.f);
            acc[mi][ni][1] = fmaxf(acc[mi][ni][1] + bf2f(z1p[mi][ni][0] >> 16), 0.f);
            acc[mi][ni][2] = fmaxf(acc[mi][ni][2] + bf2f(z1p[mi][ni][1] & 0xffffu), 0.f);
            acc[mi][ni][3] = fmaxf(acc[mi][ni][3] + bf2f(z1p[mi][ni][1] >> 16), 0.f);
        }
    ln_cw(acc, g_ln3, b_ln3, red + 3 * 128, r, kg, w, fb);   // acc = z_out

    // stage z_out (bf16) into T_sh (overwrites z1; safe: all waves passed LN2/LN3 barriers)
#pragma unroll
    for (int mi = 0; mi < 2; ++mi)
#pragma unroll
        for (int ni = 0; ni < 4; ++ni) {
            u32 w0 = cvtpk(acc[mi][ni][0], acc[mi][ni][1]);
            u32 w1 = cvtpk(acc[mi][ni][2], acc[mi][ni][3]);
#pragma unroll
            for (int j = 0; j < 4; ++j) {
                int row = mi * 16 + kg * 4 + j;
                T_sh[row * TS + fb + ni * 16 + r] =
                    (short)(((j >> 1) ? w1 : w0) >> ((j & 1) * 16));
            }
        }
    __syncthreads();

    // ======= out-GEMM: dx = z_out @ W_out (+b_out); wave w -> (mi = w&1, nb = w>>1) =======
    {
        const int mi = w & 1, nb = w >> 1;
        float bb = b_out[nb * 16 + r];
        f32x4 ao = (f32x4){bb, bb, bb, bb};
        const char* Tb = (const char*)T_sh;
#pragma unroll
        for (int ks = 0; ks < 8; ++ks) {
            int off = (mi * 16 + r) * (TS * 2) + ks * 64 + kg * 16;
            s16x8 a0 = *(const s16x8*)(Tb + off);
            s16x8 b = WpO[(ks * 2 + nb) * 64 + lane];
            ao = MFMA(a0, b, ao);
        }
#pragma unroll
        for (int j = 0; j < 4; ++j)
            out_dx[(r0 + mi * 16 + kg * 4 + j) * 32 + nb * 16 + r] = ao[j];
    }

    // ---- coalesced out_z copy: T_sh bf16 -> global f32; wave w copies rows [w*8, w*8+8) ----
    {
        float* zo = out_z + r0 * 256;
        const char* Tb = (const char*)T_sh;
#pragma unroll
        for (int it = 0; it < 4; ++it) {
            int row = w * 8 + it * 2 + (lane >> 5);
            int cs = (lane & 31) * 8;                       // col in shorts
            int4 wd = *(const int4*)(Tb + row * (TS * 2) + cs * 2);
            float4 o0, o1;
            o0.x = bf2f((u32)wd.x & 0xffffu); o0.y = bf2f((u32)wd.x >> 16);
            o0.z = bf2f((u32)wd.y & 0xffffu); o0.w = bf2f((u32)wd.y >> 16);
            o1.x = bf2f((u32)wd.z & 0xffffu); o1.y = bf2f((u32)wd.z >> 16);
            o1.z = bf2f((u32)wd.w & 0xffffu); o1.w = bf2f((u32)wd.w >> 16);
            *(float4*)(zo + row * 256 + cs) = o0;
            *(float4*)(zo + row * 256 + cs + 4) = o1;
        }
    }
}

extern "C" void kernel_launch(void* const* d_in, const int* in_sizes, int n_in,
                              void* d_out, int out_size, void* d_ws, size_t ws_size,
                              hipStream_t stream) {
    const float* x      = (const float*)d_in[0];
    const float* z      = (const float*)d_in[1];
    const float* W_inp  = (const float*)d_in[2];
    const float* b_inp  = (const float*)d_in[3];
    const float* g_lni  = (const float*)d_in[4];
    const float* b_lni  = (const float*)d_in[5];
    const float* W1     = (const float*)d_in[6];
    const float* b1     = (const float*)d_in[7];
    const float* g_ln1  = (const float*)d_in[8];
    const float* b_ln1  = (const float*)d_in[9];
    const float* W2     = (const float*)d_in[10];
    const float* b2     = (const float*)d_in[11];
    const float* g_ln2  = (const float*)d_in[12];
    const float* b_ln2  = (const float*)d_in[13];
    const float* g_ln3  = (const float*)d_in[14];
    const float* b_ln3  = (const float*)d_in[15];
    const float* W_out  = (const float*)d_in[16];
    const float* b_out  = (const float*)d_in[17];

    short* Wp1 = (short*)d_ws;            // 8*16*64*8  = 65536 bf16
    short* Wp2 = Wp1 + 65536;             // 65536
    short* WpI = Wp2 + 65536;             // 2*16*64*8  = 16384
    short* WpO = WpI + 16384;             // 8*2*64*8   = 8192

    pack_w<<<256, 256, 0, stream>>>(W1,    Wp1, 256, 256, 16, 65536);
    pack_w<<<256, 256, 0, stream>>>(W2,    Wp2, 256, 256, 16, 65536);
    pack_w<<< 64, 256, 0, stream>>>(W_inp, WpI,  48, 256, 16, 16384);
    pack_w<<< 32, 256, 0, stream>>>(W_out, WpO, 256,  32,  2,  8192);

    const long B = 262144;
    float* out_dx = (float*)d_out;
    float* out_z  = out_dx + B * 32;
    deq_main<<<B / 32, 256, 0, stream>>>(x, z, b_inp, g_lni, b_lni,
                                         b1, g_ln1, b_ln1, b2, g_ln2, b_ln2,
                                         g_ln3, b_ln3, b_out,
                                         (const s16x8*)Wp1, (const s16x8*)Wp2,
                                         (const s16x8*)WpI, (const s16x8*)WpO,
                                         out_dx, out_z);
}

// Round 11
// 283.495 us; speedup vs baseline: 3.3945x; 1.3040x over previous
//
#include <hip/hip_runtime.h>
#include <hip/hip_bf16.h>

typedef float  f32x4  __attribute__((ext_vector_type(4)));
typedef float  f32x16 __attribute__((ext_vector_type(16)));
typedef short  s16x8  __attribute__((ext_vector_type(8)));
typedef unsigned int u32;

__device__ __forceinline__ short f2bf(float f) {
    union { float f; u32 u; } c; c.f = f;
    return (short)((c.u + 0x8000u) >> 16);
}
__device__ __forceinline__ float bf2f(u32 v) {
    union { u32 u; float f; } c; c.u = v << 16; return c.f;
}
__device__ __forceinline__ u32 cvtpk(float lo, float hi) {
    u32 r;
    asm("v_cvt_pk_bf16_f32 %0, %1, %2" : "=v"(r) : "v"(lo), "v"(hi));
    return r;
}
__device__ __forceinline__ s16x8 cvt8(float4 f0, float4 f1) {
    union { s16x8 v; u32 w[4]; } u;
    u.w[0] = cvtpk(f0.x, f0.y); u.w[1] = cvtpk(f0.z, f0.w);
    u.w[2] = cvtpk(f1.x, f1.y); u.w[3] = cvtpk(f1.z, f1.w);
    return u.v;
}
__device__ __forceinline__ s16x8 cvt8v(f32x4 a, f32x4 b) {
    union { s16x8 v; u32 w[4]; } u;
    u.w[0] = cvtpk(a[0], a[1]); u.w[1] = cvtpk(a[2], a[3]);
    u.w[2] = cvtpk(b[0], b[1]); u.w[3] = cvtpk(b[2], b[3]);
    return u.v;
}
__device__ __forceinline__ void gload16(const void* g, void* l) {
    __builtin_amdgcn_global_load_lds((const __attribute__((address_space(1))) u32*)g,
                                     (__attribute__((address_space(3))) u32*)l, 16, 0, 0);
}

#define MFMA32(a, b, c) __builtin_amdgcn_mfma_f32_32x32x16_bf16((a), (b), (c), 0, 0, 0)
#define MFMA16(a, b, c) __builtin_amdgcn_mfma_f32_16x16x32_bf16((a), (b), (c), 0, 0, 0)

// ---------- pack for 16x16x32 fragments (W_out only) ----------
__global__ void pack_w(const float* __restrict__ W, short* __restrict__ out,
                       int Kreal, int N, int nbTot, int total) {
    int tid = blockIdx.x * 256 + threadIdx.x;
    if (tid >= total) return;
    int j  = tid & 7;
    int l  = (tid >> 3) & 63;
    int blk = tid >> 9;
    int nb = blk % nbTot, ks = blk / nbTot;
    int k = ks * 32 + (l >> 4) * 8 + j;
    int n = nb * 16 + (l & 15);
    out[tid] = (k < Kreal) ? f2bf(W[(long)k * N + n]) : (short)0;
}

// ---------- pack for 32x32x16 fragments: row=l&31 (feat), k=(l>>5)*8+j ----------
__global__ void pack_w32(const float* __restrict__ W, short* __restrict__ out,
                         int Kreal, int N, int nbTot, int total) {
    int tid = blockIdx.x * 256 + threadIdx.x;
    if (tid >= total) return;
    int j  = tid & 7;
    int l  = (tid >> 3) & 63;
    int blk = tid >> 9;                 // ks*nbTot + nb
    int nb = blk % nbTot, ks = blk / nbTot;
    int k = ks * 16 + (l >> 5) * 8 + j;
    int n = nb * 32 + (l & 31);
    out[tid] = (k < Kreal) ? f2bf(W[(long)k * N + n]) : (short)0;
}

// acc layout (32x32 swapped): col = batch = lane&31; feat(reg) = (reg&3)+8*(reg>>2)+4*hi
__device__ __forceinline__ void initC(f32x16& a, const float* p, int base, int hi) {
#pragma unroll
    for (int q = 0; q < 4; ++q) {
        float4 v = *(const float4*)(p + base + q * 8 + hi * 4);
        a[q * 4 + 0] = v.x; a[q * 4 + 1] = v.y; a[q * 4 + 2] = v.z; a[q * 4 + 3] = v.w;
    }
}
__device__ __forceinline__ void addC(f32x16& a, const float* p, int base, int hi) {
#pragma unroll
    for (int q = 0; q < 4; ++q) {
        float4 v = *(const float4*)(p + base + q * 8 + hi * 4);
        a[q * 4 + 0] += v.x; a[q * 4 + 1] += v.y; a[q * 4 + 2] += v.z; a[q * 4 + 3] += v.w;
    }
}

// ---------- layernorm over 256 feats; batch = lane&31, wave owns 64 feats ----------
__device__ __forceinline__ void ln32(f32x16& a0, f32x16& a1,
                                     const float* __restrict__ g, const float* __restrict__ bl,
                                     float2* red, int lane, int b, int hi, int w, int fb) {
    float s = 0.f, q = 0.f;
#pragma unroll
    for (int i = 0; i < 16; ++i) {
        s += a0[i] + a1[i];
        q += a0[i] * a0[i] + a1[i] * a1[i];
    }
    s += __shfl_xor(s, 32); q += __shfl_xor(q, 32);
    if (lane < 32) red[b * 4 + w] = make_float2(s, q);
    __syncthreads();
    float2 p0 = red[b * 4 + 0], p1 = red[b * 4 + 1];
    float2 p2 = red[b * 4 + 2], p3 = red[b * 4 + 3];
    float S = (p0.x + p1.x) + (p2.x + p3.x);
    float Q = (p0.y + p1.y) + (p2.y + p3.y);
    float mean = S * (1.f / 256.f);
    float var  = fmaxf(Q * (1.f / 256.f) - mean * mean, 0.f);
    float rstd = rsqrtf(var + 1e-5f);
#pragma unroll
    for (int nb = 0; nb < 2; ++nb) {
        f32x16& a = nb ? a1 : a0;
#pragma unroll
        for (int qd = 0; qd < 4; ++qd) {
            float4 gv = *(const float4*)(g  + fb + nb * 32 + qd * 8 + hi * 4);
            float4 bv = *(const float4*)(bl + fb + nb * 32 + qd * 8 + hi * 4);
            a[qd * 4 + 0] = (a[qd * 4 + 0] - mean) * rstd * gv.x + bv.x;
            a[qd * 4 + 1] = (a[qd * 4 + 1] - mean) * rstd * gv.y + bv.y;
            a[qd * 4 + 2] = (a[qd * 4 + 2] - mean) * rstd * gv.z + bv.z;
            a[qd * 4 + 3] = (a[qd * 4 + 3] - mean) * rstd * gv.w + bv.w;
        }
    }
}

// ---------------- main fused kernel: 4 waves, 32 batch rows, 32x32 MFMA ----------------
__global__ __launch_bounds__(256, 4) void deq_main(
    const float* __restrict__ x, const float* __restrict__ z,
    const float* __restrict__ b_inp, const float* __restrict__ g_lni, const float* __restrict__ b_lni,
    const float* __restrict__ b1, const float* __restrict__ g_ln1, const float* __restrict__ b_ln1,
    const float* __restrict__ b2, const float* __restrict__ g_ln2, const float* __restrict__ b_ln2,
    const float* __restrict__ g_ln3, const float* __restrict__ b_ln3,
    const float* __restrict__ b_out,
    const s16x8* __restrict__ Wp1, const s16x8* __restrict__ Wp2,
    const s16x8* __restrict__ WpI, const s16x8* __restrict__ WpO,
    float* __restrict__ out_dx, float* __restrict__ out_z)
{
    // [0,32K): z-tile f32 (32 rows x 1KB, src-swizzled), overlaid by T_sh
    // ([32][256] bf16, 512B rows, XOR-swizzled) after LN1's barrier. [32K,36K): LN stats.
    __shared__ __align__(16) char smem[36 * 1024];
    short*  T_sh = (short*)smem;
    float2* red  = (float2*)(smem + 32 * 1024);

    const int tid  = threadIdx.x;
    const int w    = tid >> 6;
    const int lane = tid & 63;
    const int b    = lane & 31;       // batch row
    const int hi   = lane >> 5;       // k-half / feat-offset selector
    const int fb   = w * 64;          // wave's feature base
    const int fbn  = w * 2;           // wave's 32-feat block base
    const int r = lane & 15, kg = lane >> 4;   // out-GEMM 16x16 indices
    const long r0 = (long)blockIdx.x * 32;
    const int swzb = (b & 7) << 4;

    // ---- DMA: stage z tile; wave w stages rows [w*8, w*8+8) (src pre-swizzled) ----
#pragma unroll
    for (int i = 0; i < 8; ++i) {
        int row = w * 8 + i;
        const char* gp = (const char*)(z + (r0 + row) * 256) + ((lane * 16) ^ ((row & 7) << 4));
        gload16(gp, smem + row * 1024);
    }

    // x loads early (latency under the staging barrier): lane's batch row b
    float4 xv0, xv1, xv2, xv3, xv4, xv5;
    {
        const float* xr = x + (r0 + b) * 48 + hi * 8;
        xv0 = ((const float4*)(xr))[0];      xv1 = ((const float4*)(xr + 4))[0];
        xv2 = ((const float4*)(xr + 16))[0]; xv3 = ((const float4*)(xr + 20))[0];
        xv4 = ((const float4*)(xr + 32))[0]; xv5 = ((const float4*)(xr + 36))[0];
    }
    __syncthreads();   // DMA drained

    f32x16 acc0, acc1;

    // ================= GEMM1: C = W1^T · z^T (+b1), A-frags from LDS z ==============
    initC(acc0, b1, fb, hi);
    initC(acc1, b1, fb + 32, hi);
    {
        const char* zrow = (const char*)smem + b * 1024;
        s16x8 c0 = Wp1[(fbn + 0) * 64 + lane];
        s16x8 c1 = Wp1[(fbn + 1) * 64 + lane];
#pragma unroll
        for (int ks = 0; ks < 16; ++ks) {
            s16x8 n0, n1;
            if (ks < 15) {
                n0 = Wp1[((ks + 1) * 8 + fbn + 0) * 64 + lane];
                n1 = Wp1[((ks + 1) * 8 + fbn + 1) * 64 + lane];
            }
            const int c = ks * 64 + hi * 32;
            f32x4 p0 = *(const f32x4*)(zrow + ((c) ^ swzb));
            f32x4 p1 = *(const f32x4*)(zrow + ((c + 16) ^ swzb));
            s16x8 a = cvt8v(p0, p1);
            acc0 = MFMA32(c0, a, acc0);
            acc1 = MFMA32(c1, a, acc1);
            c0 = n0; c1 = n1;
        }
    }

    // relu + LN1 -> z1
#pragma unroll
    for (int i = 0; i < 16; ++i) { acc0[i] = fmaxf(acc0[i], 0.f); acc1[i] = fmaxf(acc1[i], 0.f); }
    ln32(acc0, acc1, g_ln1, b_ln1, red + 0 * 128, lane, b, hi, w, fb);

    // pack z1 (regs, residual) + stage to T_sh ([b][256] bf16, XOR-swizzled)
    u32 z1p[2][8];
#pragma unroll
    for (int nb = 0; nb < 2; ++nb) {
        f32x16& a = nb ? acc1 : acc0;
#pragma unroll
        for (int qd = 0; qd < 4; ++qd) {
            z1p[nb][qd * 2 + 0] = cvtpk(a[qd * 4 + 0], a[qd * 4 + 1]);
            z1p[nb][qd * 2 + 1] = cvtpk(a[qd * 4 + 2], a[qd * 4 + 3]);
        }
    }
#pragma unroll
    for (int nb = 0; nb < 2; ++nb)
#pragma unroll
        for (int qd = 0; qd < 4; ++qd) {
            int fbyte = (fb + nb * 32 + qd * 8 + hi * 4) * 2;
            *(uint2*)((char*)T_sh + b * 512 + (fbyte ^ swzb)) =
                make_uint2(z1p[nb][qd * 2], z1p[nb][qd * 2 + 1]);
        }

    // ================= x-GEMM: C = W_inp^T · x^T (+b_inp) =================
    initC(acc0, b_inp, fb, hi);
    initC(acc1, b_inp, fb + 32, hi);
    {
        s16x8 a0 = cvt8(xv0, xv1);
        s16x8 a1 = cvt8(xv2, xv3);
        s16x8 a2 = cvt8(xv4, xv5);
        acc0 = MFMA32(WpI[(0 * 8 + fbn + 0) * 64 + lane], a0, acc0);
        acc1 = MFMA32(WpI[(0 * 8 + fbn + 1) * 64 + lane], a0, acc1);
        acc0 = MFMA32(WpI[(1 * 8 + fbn + 0) * 64 + lane], a1, acc0);
        acc1 = MFMA32(WpI[(1 * 8 + fbn + 1) * 64 + lane], a1, acc1);
        acc0 = MFMA32(WpI[(2 * 8 + fbn + 0) * 64 + lane], a2, acc0);
        acc1 = MFMA32(WpI[(2 * 8 + fbn + 1) * 64 + lane], a2, acc1);
    }
    // LN_inp (barrier also orders all waves' z1 staging before GEMM2 reads)
    ln32(acc0, acc1, g_lni, b_lni, red + 1 * 128, lane, b, hi, w, fb);

    // + b2 (C-init for GEMM2)
    addC(acc0, b2, fb, hi);
    addC(acc1, b2, fb + 32, hi);

    // ================= GEMM2: C += W2^T · z1^T (z1-frags from T_sh) =================
    {
        const char* zr = (const char*)T_sh + b * 512;
        s16x8 c0 = Wp2[(fbn + 0) * 64 + lane];
        s16x8 c1 = Wp2[(fbn + 1) * 64 + lane];
#pragma unroll
        for (int ks = 0; ks < 16; ++ks) {
            s16x8 n0, n1;
            if (ks < 15) {
                n0 = Wp2[((ks + 1) * 8 + fbn + 0) * 64 + lane];
                n1 = Wp2[((ks + 1) * 8 + fbn + 1) * 64 + lane];
            }
            s16x8 az = *(const s16x8*)(zr + ((ks * 32 + hi * 16) ^ swzb));
            acc0 = MFMA32(c0, az, acc0);
            acc1 = MFMA32(c1, az, acc1);
            c0 = n0; c1 = n1;
        }
    }
    ln32(acc0, acc1, g_ln2, b_ln2, red + 2 * 128, lane, b, hi, w, fb);   // inner

    // ---- z_out = LN3(relu(z1 + inner)); z1 from registers ----
#pragma unroll
    for (int nb = 0; nb < 2; ++nb) {
        f32x16& a = nb ? acc1 : acc0;
#pragma unroll
        for (int qd = 0; qd < 4; ++qd) {
            a[qd * 4 + 0] = fmaxf(a[qd * 4 + 0] + bf2f(z1p[nb][qd * 2] & 0xffffu), 0.f);
            a[qd * 4 + 1] = fmaxf(a[qd * 4 + 1] + bf2f(z1p[nb][qd * 2] >> 16), 0.f);
            a[qd * 4 + 2] = fmaxf(a[qd * 4 + 2] + bf2f(z1p[nb][qd * 2 + 1] & 0xffffu), 0.f);
            a[qd * 4 + 3] = fmaxf(a[qd * 4 + 3] + bf2f(z1p[nb][qd * 2 + 1] >> 16), 0.f);
        }
    }
    ln32(acc0, acc1, g_ln3, b_ln3, red + 3 * 128, lane, b, hi, w, fb);   // z_out

    // stage z_out to T_sh (overwrites z1 — safe past LN2/LN3 barriers)
#pragma unroll
    for (int nb = 0; nb < 2; ++nb) {
        f32x16& a = nb ? acc1 : acc0;
#pragma unroll
        for (int qd = 0; qd < 4; ++qd) {
            u32 w0 = cvtpk(a[qd * 4 + 0], a[qd * 4 + 1]);
            u32 w1 = cvtpk(a[qd * 4 + 2], a[qd * 4 + 3]);
            int fbyte = (fb + nb * 32 + qd * 8 + hi * 4) * 2;
            *(uint2*)((char*)T_sh + b * 512 + (fbyte ^ swzb)) = make_uint2(w0, w1);
        }
    }
    __syncthreads();

    // ======= out-GEMM (16x16 path): dx = z_out @ W_out (+b_out); wave -> (mi, nbo) =======
    {
        const int mi = w & 1, nbo = w >> 1;
        float bb = b_out[nbo * 16 + r];
        f32x4 ao = (f32x4){bb, bb, bb, bb};
#pragma unroll
        for (int ks = 0; ks < 8; ++ks) {
            int R = mi * 16 + r;
            int off = R * 512 + ((ks * 64 + kg * 16) ^ ((R & 7) << 4));
            s16x8 a0 = *(const s16x8*)((const char*)T_sh + off);
            s16x8 bw = WpO[(ks * 2 + nbo) * 64 + lane];
            ao = MFMA16(a0, bw, ao);
        }
#pragma unroll
        for (int j = 0; j < 4; ++j)
            out_dx[(r0 + mi * 16 + kg * 4 + j) * 32 + nbo * 16 + r] = ao[j];
    }

    // ---- coalesced out_z: T_sh bf16 -> f32; wave w copies rows [w*8, w*8+8) ----
    {
        float* zo = out_z + r0 * 256;
#pragma unroll
        for (int it = 0; it < 4; ++it) {
            int row = w * 8 + it * 2 + (lane >> 5);
            int addr = row * 512 + (((lane & 31) * 16) ^ ((row & 7) << 4));
            int4 wd = *(const int4*)((const char*)T_sh + addr);
            float4 o0, o1;
            o0.x = bf2f((u32)wd.x & 0xffffu); o0.y = bf2f((u32)wd.x >> 16);
            o0.z = bf2f((u32)wd.y & 0xffffu); o0.w = bf2f((u32)wd.y >> 16);
            o1.x = bf2f((u32)wd.z & 0xffffu); o1.y = bf2f((u32)wd.z >> 16);
            o1.z = bf2f((u32)wd.w & 0xffffu); o1.w = bf2f((u32)wd.w >> 16);
            int e = row * 256 + (lane & 31) * 8;
            *(float4*)(zo + e) = o0;
            *(float4*)(zo + e + 4) = o1;
        }
    }
}

extern "C" void kernel_launch(void* const* d_in, const int* in_sizes, int n_in,
                              void* d_out, int out_size, void* d_ws, size_t ws_size,
                              hipStream_t stream) {
    const float* x      = (const float*)d_in[0];
    const float* z      = (const float*)d_in[1];
    const float* W_inp  = (const float*)d_in[2];
    const float* b_inp  = (const float*)d_in[3];
    const float* g_lni  = (const float*)d_in[4];
    const float* b_lni  = (const float*)d_in[5];
    const float* W1     = (const float*)d_in[6];
    const float* b1     = (const float*)d_in[7];
    const float* g_ln1  = (const float*)d_in[8];
    const float* b_ln1  = (const float*)d_in[9];
    const float* W2     = (const float*)d_in[10];
    const float* b2     = (const float*)d_in[11];
    const float* g_ln2  = (const float*)d_in[12];
    const float* b_ln2  = (const float*)d_in[13];
    const float* g_ln3  = (const float*)d_in[14];
    const float* b_ln3  = (const float*)d_in[15];
    const float* W_out  = (const float*)d_in[16];
    const float* b_out  = (const float*)d_in[17];

    short* Wp1 = (short*)d_ws;            // 16ks*8nb*512 = 65536 bf16 (32x32 frags)
    short* Wp2 = Wp1 + 65536;             // 65536
    short* WpI = Wp2 + 65536;             // 3ks*8nb*512  = 12288
    short* WpO = WpI + 12288;             // 8*2*512      = 8192 (16x16 frags)

    pack_w32<<<256, 256, 0, stream>>>(W1,    Wp1, 256, 256, 8, 65536);
    pack_w32<<<256, 256, 0, stream>>>(W2,    Wp2, 256, 256, 8, 65536);
    pack_w32<<< 48, 256, 0, stream>>>(W_inp, WpI,  48, 256, 8, 12288);
    pack_w  <<< 32, 256, 0, stream>>>(W_out, WpO, 256,  32, 2,  8192);

    const long B = 262144;
    float* out_dx = (float*)d_out;
    float* out_z  = out_dx + B * 32;
    deq_main<<<B / 32, 256, 0, stream>>>(x, z, b_inp, g_lni, b_lni,
                                         b1, g_ln1, b_ln1, b2, g_ln2, b_ln2,
                                         g_ln3, b_ln3, b_out,
                                         (const s16x8*)Wp1, (const s16x8*)Wp2,
                                         (const s16x8*)WpI, (const s16x8*)WpO,
                                         out_dx, out_z);
}